// Round 4
// baseline (879.298 us; speedup 1.0000x reference)
//
#include <hip/hip_runtime.h>
#include <hip/hip_bf16.h>
#include <cstdint>
#include <cstddef>

#define N_NODES 50000
#define N_EDGES 800000
#define D_FEAT  128
#define HALF    64
#define HIDDEN  256
#define LABELS  40

#define SCAN_BLOCKS 49   // 49 * 1024 = 50176 >= N_NODES

#define NCHUNK      50     // CSR build chunks
#define CHUNK_NODES 1000   // nodes per chunk (50 * 1000 = 50000)
#define SEG_CAP     24000  // LDS segment capacity (ints); E[seg]=16k, sigma~126

typedef __attribute__((ext_vector_type(8))) short bf16x8;
typedef __attribute__((ext_vector_type(4))) float f32x4;

// Packed-weight layout offsets (in bf16 elements).
#define PK_SELF(L) ((size_t)(L) * 8192)
#define PK_NBR(L)  (24576 + (size_t)(L) * 8192)
#define PK_W1      49152
#define PK_W2      81920
#define PK_TOTAL   94208

__device__ inline uint16_t f2bf_bits(float f) {
    __hip_bfloat16 b = __float2bfloat16(f);
    uint16_t u; __builtin_memcpy(&u, &b, 2); return u;
}

// ---------------------------------------------------------------------------
// CSR build, scatter-free: chunk-owned LDS counting + LDS bucket fill.
// Each block owns 1000 nodes and scans the full edge list (L2/L3-resident).
// ---------------------------------------------------------------------------
__global__ __launch_bounds__(1024) void chunk_count_kernel(
        const int* __restrict__ row, int* __restrict__ deg) {
    __shared__ int cnt[CHUNK_NODES];
    int tid = threadIdx.x;
    int c0  = blockIdx.x * CHUNK_NODES;
    for (int i = tid; i < CHUNK_NODES; i += 1024) cnt[i] = 0;
    __syncthreads();
    for (int e = tid; e < N_EDGES; e += 1024) {
        int r = row[e];                       // coalesced, cached
        unsigned d = (unsigned)(r - c0);
        if (d < CHUNK_NODES) atomicAdd(&cnt[d], 1);
    }
    __syncthreads();
    for (int i = tid; i < CHUNK_NODES; i += 1024) deg[c0 + i] = cnt[i];
}

__global__ __launch_bounds__(1024) void chunk_fill_kernel(
        const int* __restrict__ row, const int* __restrict__ col,
        const int* __restrict__ rowstart, int* __restrict__ csr_col) {
    __shared__ int cur[CHUNK_NODES];
    __shared__ int seg[SEG_CAP];
    int tid = threadIdx.x;
    int c0  = blockIdx.x * CHUNK_NODES;
    int segbase = rowstart[c0];
    int segend  = (blockIdx.x == NCHUNK - 1) ? N_EDGES : rowstart[c0 + CHUNK_NODES];
    for (int i = tid; i < CHUNK_NODES; i += 1024)
        cur[i] = rowstart[c0 + i] - segbase;   // LDS-relative cursors
    __syncthreads();
    for (int e = tid; e < N_EDGES; e += 1024) {
        int r = row[e];
        unsigned d = (unsigned)(r - c0);
        if (d < CHUNK_NODES) {
            int p = atomicAdd(&cur[d], 1);
            if (p < SEG_CAP) seg[p] = col[e];  // clamp: LDS-safety only
        }
    }
    __syncthreads();
    int n = segend - segbase;
    for (int i = tid; i < n; i += 1024)
        csr_col[segbase + i] = seg[i];         // fully coalesced write
}

// ---------------------------------------------------------------------------
// 3-phase parallel scan of deg -> rowstart (+ inv_deg)
// ---------------------------------------------------------------------------
__global__ __launch_bounds__(1024) void scan1_kernel(
        const int* __restrict__ deg, int* __restrict__ rowstart,
        float* __restrict__ inv_deg, int* __restrict__ blocksum) {
    __shared__ int wtot[16];
    int tid  = threadIdx.x;
    int i    = blockIdx.x * 1024 + tid;
    int lane = tid & 63;
    int wid  = tid >> 6;
    int v    = (i < N_NODES) ? deg[i] : 0;
    int s    = v;
#pragma unroll
    for (int off = 1; off < 64; off <<= 1) {
        int t = __shfl_up(s, off, 64);
        if (lane >= off) s += t;
    }
    if (lane == 63) wtot[wid] = s;
    __syncthreads();
    if (wid == 0) {
        int wv = (lane < 16) ? wtot[lane] : 0;
        int ws = wv;
#pragma unroll
        for (int off = 1; off < 16; off <<= 1) {
            int t = __shfl_up(ws, off, 64);
            if (lane >= off) ws += t;
        }
        if (lane < 16) wtot[lane] = ws - wv;
        if (lane == 15 && blocksum) blocksum[blockIdx.x] = ws;
    }
    __syncthreads();
    if (i < N_NODES) {
        rowstart[i] = wtot[wid] + s - v;
        inv_deg[i]  = 1.0f / fmaxf((float)v, 1.0f);
    }
}

__global__ void scan2_kernel(int* __restrict__ blocksum) {
    int lane = threadIdx.x;
    int v = (lane < SCAN_BLOCKS) ? blocksum[lane] : 0;
    int s = v;
#pragma unroll
    for (int off = 1; off < 64; off <<= 1) {
        int t = __shfl_up(s, off, 64);
        if (lane >= off) s += t;
    }
    if (lane < SCAN_BLOCKS) blocksum[lane] = s - v;
}

__global__ __launch_bounds__(1024) void scan3_kernel(
        int* __restrict__ rowstart, const int* __restrict__ blocksum) {
    int i = blockIdx.x * 1024 + threadIdx.x;
    if (i < N_NODES) rowstart[i] += blocksum[blockIdx.x];
}

// ---------------------------------------------------------------------------
// x (fp32) -> bf16
// ---------------------------------------------------------------------------
__global__ __launch_bounds__(256) void xcast_kernel(
        const float* __restrict__ x, __hip_bfloat16* __restrict__ xb) {
    size_t i = (size_t)(blockIdx.x * blockDim.x + threadIdx.x) * 4;
    if (i >= (size_t)N_NODES * D_FEAT) return;
    float4 v = *(const float4*)(x + i);
    uint2 p;
    p.x = (uint32_t)f2bf_bits(v.x) | ((uint32_t)f2bf_bits(v.y) << 16);
    p.y = (uint32_t)f2bf_bits(v.z) | ((uint32_t)f2bf_bits(v.w) << 16);
    *(uint2*)((uint16_t*)xb + i) = p;
}

// ---------------------------------------------------------------------------
// Pack all weights to bf16 in MFMA B-fragment order.
//   pack[((ns*ksteps + ks)*64 + l)*8 + j] = W[ks*32 + (l>>4)*8 + j][ns*16 + (l&15)]
// ---------------------------------------------------------------------------
__global__ __launch_bounds__(256) void pack_all_kernel(
        const float* __restrict__ selfk, const float* __restrict__ nbrk,
        const float* __restrict__ w1, const float* __restrict__ w2,
        __hip_bfloat16* __restrict__ wpack) {
    int m = blockIdx.y;
    const float* W; int K, Ncols, Npad; size_t dstoff;
    if (m < 3)      { W = selfk + (size_t)m*D_FEAT*HALF;      K=128; Ncols=64;  Npad=64;  dstoff = PK_SELF(m); }
    else if (m < 6) { W = nbrk  + (size_t)(m-3)*D_FEAT*HALF;  K=128; Ncols=64;  Npad=64;  dstoff = PK_NBR(m-3); }
    else if (m == 6){ W = w1;                                 K=128; Ncols=256; Npad=256; dstoff = PK_W1; }
    else            { W = w2;                                 K=256; Ncols=40;  Npad=48;  dstoff = PK_W2; }
    int ksteps = K / 32;
    int total  = ksteps * (Npad / 16) * 64;
    int t = blockIdx.x * blockDim.x + threadIdx.x;
    if (t >= total) return;
    int lane = t & 63;
    int rest = t >> 6;
    int ks   = rest % ksteps;
    int ns   = rest / ksteps;
    int colb = ns * 16 + (lane & 15);
    int kb   = ks * 32 + (lane >> 4) * 8;
    __hip_bfloat16* dst = wpack + dstoff + (size_t)t * 8;
#pragma unroll
    for (int j = 0; j < 8; j++) {
        float v = (colb < Ncols) ? W[(size_t)(kb + j) * Ncols + colb] : 0.f;
        dst[j] = __float2bfloat16(v);
    }
}

// ---------------------------------------------------------------------------
// Mean-neighbor aggregation (bf16): one wave per node, 4B (2 bf16) per lane.
// ---------------------------------------------------------------------------
__global__ __launch_bounds__(256) void agg_kernel(
        const __hip_bfloat16* __restrict__ h, const int* __restrict__ csr_col,
        const int* __restrict__ rowstart, const int* __restrict__ deg,
        const float* __restrict__ inv_deg, __hip_bfloat16* __restrict__ nbr) {
    int gid  = blockIdx.x * blockDim.x + threadIdx.x;
    int node = gid >> 6;
    int lane = threadIdx.x & 63;
    if (node >= N_NODES) return;
    int start = rowstart[node];
    int d     = deg[node];
    const uint32_t* hw = (const uint32_t*)h;   // row = 64 dwords
    float a0 = 0.f, a1 = 0.f;
    int j = 0;
    for (; j + 4 <= d; j += 4) {
        int s0 = csr_col[start + j + 0];
        int s1 = csr_col[start + j + 1];
        int s2 = csr_col[start + j + 2];
        int s3 = csr_col[start + j + 3];
        uint32_t u0 = hw[(size_t)s0 * 64 + lane];
        uint32_t u1 = hw[(size_t)s1 * 64 + lane];
        uint32_t u2 = hw[(size_t)s2 * 64 + lane];
        uint32_t u3 = hw[(size_t)s3 * 64 + lane];
        a0 += __uint_as_float(u0 << 16) + __uint_as_float(u1 << 16)
            + __uint_as_float(u2 << 16) + __uint_as_float(u3 << 16);
        a1 += __uint_as_float(u0 & 0xffff0000u) + __uint_as_float(u1 & 0xffff0000u)
            + __uint_as_float(u2 & 0xffff0000u) + __uint_as_float(u3 & 0xffff0000u);
    }
    for (; j < d; ++j) {
        int s = csr_col[start + j];
        uint32_t u = hw[(size_t)s * 64 + lane];
        a0 += __uint_as_float(u << 16);
        a1 += __uint_as_float(u & 0xffff0000u);
    }
    float inv = inv_deg[node];
    uint32_t pv = (uint32_t)f2bf_bits(a0 * inv) | ((uint32_t)f2bf_bits(a1 * inv) << 16);
    ((uint32_t*)nbr)[(size_t)node * 64 + lane] = pv;
}

// ---------------------------------------------------------------------------
// Layer GEMM (MFMA): out[N,128] = relu([h@Wself | nbr@Wnbr] + bias), bf16 out.
// ---------------------------------------------------------------------------
__global__ __launch_bounds__(256) void layer_mfma_kernel(
        const __hip_bfloat16* __restrict__ h, const __hip_bfloat16* __restrict__ nbr,
        const __hip_bfloat16* __restrict__ wpack_self,
        const __hip_bfloat16* __restrict__ wpack_nbr,
        const float* __restrict__ bias, __hip_bfloat16* __restrict__ out) {
    int wave = threadIdx.x >> 6, lane = threadIdx.x & 63;
    int half = wave >> 1;                       // 0: self(h), 1: nbr
    int row0 = blockIdx.x * 32 + (wave & 1) * 16;
    if (row0 >= N_NODES) return;
    int lrow = lane & 15, lgrp = lane >> 4;
    const __hip_bfloat16* A  = half ? nbr : h;
    const __hip_bfloat16* wp = half ? wpack_nbr : wpack_self;
    const __hip_bfloat16* arow = A + (size_t)(row0 + lrow) * D_FEAT + lgrp * 8;

    f32x4 acc[4] = {};
    for (int ks = 0; ks < 4; ks++) {
        bf16x8 af = *(const bf16x8*)(arow + ks * 32);
#pragma unroll
        for (int ns = 0; ns < 4; ns++) {
            bf16x8 bfr = *(const bf16x8*)(wp + ((size_t)(ns * 4 + ks) * 64 + lane) * 8);
            acc[ns] = __builtin_amdgcn_mfma_f32_16x16x32_bf16(af, bfr, acc[ns], 0, 0, 0);
        }
    }
    int colbase = half * 64;
#pragma unroll
    for (int ns = 0; ns < 4; ns++) {
        int col = colbase + ns * 16 + lrow;
        float bv = bias[col];
#pragma unroll
        for (int i = 0; i < 4; i++) {
            int r = row0 + lgrp * 4 + i;
            float v = fmaxf(acc[ns][i] + bv, 0.f);
            out[(size_t)r * D_FEAT + col] = __float2bfloat16(v);
        }
    }
}

// ---------------------------------------------------------------------------
// MLP1 (MFMA): hidden[N,256] = relu(h @ W1 + b1), bf16 out. Wave = 16 rows.
// ---------------------------------------------------------------------------
__global__ __launch_bounds__(256) void mlp1_mfma_kernel(
        const __hip_bfloat16* __restrict__ h, const __hip_bfloat16* __restrict__ w1p,
        const float* __restrict__ b1, __hip_bfloat16* __restrict__ hidden) {
    int wave = threadIdx.x >> 6, lane = threadIdx.x & 63;
    int row0 = blockIdx.x * 64 + wave * 16;
    if (row0 >= N_NODES) return;
    int lrow = lane & 15, lgrp = lane >> 4;
    const __hip_bfloat16* arow = h + (size_t)(row0 + lrow) * D_FEAT + lgrp * 8;

    f32x4 acc[16] = {};
    for (int ks = 0; ks < 4; ks++) {
        bf16x8 af = *(const bf16x8*)(arow + ks * 32);
#pragma unroll
        for (int ns = 0; ns < 16; ns++) {
            bf16x8 bfr = *(const bf16x8*)(w1p + ((size_t)(ns * 4 + ks) * 64 + lane) * 8);
            acc[ns] = __builtin_amdgcn_mfma_f32_16x16x32_bf16(af, bfr, acc[ns], 0, 0, 0);
        }
    }
#pragma unroll
    for (int ns = 0; ns < 16; ns++) {
        int col = ns * 16 + lrow;
        float bv = b1[col];
#pragma unroll
        for (int i = 0; i < 4; i++) {
            int r = row0 + lgrp * 4 + i;
            float v = fmaxf(acc[ns][i] + bv, 0.f);
            hidden[(size_t)r * HIDDEN + col] = __float2bfloat16(v);
        }
    }
}

// ---------------------------------------------------------------------------
// MLP2 (MFMA): out[N,40] = hidden @ W2 + b2 (fp32 out, N padded 40->48).
// ---------------------------------------------------------------------------
__global__ __launch_bounds__(256) void mlp2_mfma_kernel(
        const __hip_bfloat16* __restrict__ hidden, const __hip_bfloat16* __restrict__ w2p,
        const float* __restrict__ b2, float* __restrict__ out) {
    int wave = threadIdx.x >> 6, lane = threadIdx.x & 63;
    int row0 = blockIdx.x * 64 + wave * 16;
    if (row0 >= N_NODES) return;
    int lrow = lane & 15, lgrp = lane >> 4;
    const __hip_bfloat16* arow = hidden + (size_t)(row0 + lrow) * HIDDEN + lgrp * 8;

    f32x4 acc[3] = {};
    for (int ks = 0; ks < 8; ks++) {
        bf16x8 af = *(const bf16x8*)(arow + ks * 32);
#pragma unroll
        for (int ns = 0; ns < 3; ns++) {
            bf16x8 bfr = *(const bf16x8*)(w2p + ((size_t)(ns * 8 + ks) * 64 + lane) * 8);
            acc[ns] = __builtin_amdgcn_mfma_f32_16x16x32_bf16(af, bfr, acc[ns], 0, 0, 0);
        }
    }
#pragma unroll
    for (int ns = 0; ns < 3; ns++) {
        int col = ns * 16 + lrow;
        if (col < LABELS) {
            float bv = b2[col];
#pragma unroll
            for (int i = 0; i < 4; i++) {
                int r = row0 + lgrp * 4 + i;
                out[(size_t)r * LABELS + col] = acc[ns][i] + bv;
            }
        }
    }
}

// ---------------------------------------------------------------------------
extern "C" void kernel_launch(void* const* d_in, const int* in_sizes, int n_in,
                              void* d_out, int out_size, void* d_ws, size_t ws_size,
                              hipStream_t stream) {
    const float* x      = (const float*)d_in[0];
    const int*   ei     = (const int*)d_in[1];
    const float* selfk  = (const float*)d_in[2];
    const float* nbrk   = (const float*)d_in[3];
    const float* biases = (const float*)d_in[4];
    const float* w1     = (const float*)d_in[5];
    const float* b1     = (const float*)d_in[6];
    const float* w2     = (const float*)d_in[7];
    const float* b2     = (const float*)d_in[8];
    float* out = (float*)d_out;

    const int* row = ei;             // targets
    const int* col = ei + N_EDGES;   // sources

    char* ws = (char*)d_ws;
    size_t off = 0;
    auto alloc = [&](size_t bytes) -> char* {
        char* p = ws + off;
        off = (off + bytes + 255) & ~(size_t)255;
        return p;
    };
    int*   deg      = (int*)  alloc((size_t)N_NODES * 4);
    int*   rowstart = (int*)  alloc((size_t)N_NODES * 4);
    float* inv_deg  = (float*)alloc((size_t)N_NODES * 4);
    int*   blocksum = (int*)  alloc((size_t)SCAN_BLOCKS * 4);
    int*   csr_col  = (int*)  alloc((size_t)N_EDGES * 4);
    __hip_bfloat16* wpack  = (__hip_bfloat16*)alloc(PK_TOTAL * 2);
    __hip_bfloat16* xb     = (__hip_bfloat16*)alloc((size_t)N_NODES * D_FEAT * 2);
    __hip_bfloat16* hA     = (__hip_bfloat16*)alloc((size_t)N_NODES * D_FEAT * 2);
    __hip_bfloat16* hB     = (__hip_bfloat16*)alloc((size_t)N_NODES * D_FEAT * 2);
    __hip_bfloat16* nbrbuf = (__hip_bfloat16*)alloc((size_t)N_NODES * D_FEAT * 2);
    __hip_bfloat16* hidden = (__hip_bfloat16*)alloc((size_t)N_NODES * HIDDEN * 2);

    chunk_count_kernel<<<NCHUNK, 1024, 0, stream>>>(row, deg);
    scan1_kernel<<<SCAN_BLOCKS, 1024, 0, stream>>>(deg, rowstart, inv_deg, blocksum);
    scan2_kernel<<<1, 64, 0, stream>>>(blocksum);
    scan3_kernel<<<SCAN_BLOCKS, 1024, 0, stream>>>(rowstart, blocksum);
    chunk_fill_kernel<<<NCHUNK, 1024, 0, stream>>>(row, col, rowstart, csr_col);

    xcast_kernel<<<(N_NODES * D_FEAT / 4 + 255) / 256, 256, 0, stream>>>(x, xb);
    dim3 pgrid(16, 8);
    pack_all_kernel<<<pgrid, 256, 0, stream>>>(selfk, nbrk, w1, w2, wpack);

    const int agg_blocks   = (N_NODES * 64 + 255) / 256;   // one wave per node
    const int layer_blocks = (N_NODES + 31) / 32;
    const int mlp_blocks   = (N_NODES + 63) / 64;

    const __hip_bfloat16* hcur = xb;
    __hip_bfloat16* bufs[3] = {hA, hB, hA};
    for (int L = 0; L < 3; L++) {
        agg_kernel<<<agg_blocks, 256, 0, stream>>>(hcur, csr_col, rowstart, deg,
                                                   inv_deg, nbrbuf);
        layer_mfma_kernel<<<layer_blocks, 256, 0, stream>>>(
            hcur, nbrbuf, wpack + PK_SELF(L), wpack + PK_NBR(L),
            biases + (size_t)L * (2 * HALF), bufs[L]);
        hcur = bufs[L];
    }

    mlp1_mfma_kernel<<<mlp_blocks, 256, 0, stream>>>(hcur, wpack + PK_W1, b1, hidden);
    mlp2_mfma_kernel<<<mlp_blocks, 256, 0, stream>>>(hidden, wpack + PK_W2, b2, out);
}

// Round 5
// 305.425 us; speedup vs baseline: 2.8789x; 2.8789x over previous
//
#include <hip/hip_runtime.h>
#include <hip/hip_bf16.h>
#include <cstdint>
#include <cstddef>

#define N_NODES 50000
#define N_EDGES 800000
#define D_FEAT  128
#define HALF    64
#define HIDDEN  256
#define LABELS  40

#define NBUCK 196        // ceil(50000/256) buckets of 256 nodes (node>>8)
#define BCAP  5632       // staging cap per bucket; E[cnt]=4096, sigma~64 (24 sigma)
#define EDGES_PER_BLK 4096

typedef __attribute__((ext_vector_type(8))) short bf16x8;
typedef __attribute__((ext_vector_type(4))) float f32x4;

// Packed-weight layout offsets (in bf16 elements).
#define PK_SELF(L) ((size_t)(L) * 8192)
#define PK_NBR(L)  (24576 + (size_t)(L) * 8192)
#define PK_W1      49152
#define PK_W2      81920
#define PK_TOTAL   94208

__device__ inline uint16_t f2bf_bits(float f) {
    __hip_bfloat16 b = __float2bfloat16(f);
    uint16_t u; __builtin_memcpy(&u, &b, 2); return u;
}

// ---------------------------------------------------------------------------
// CSR build phase 1: bucket scatter. 196 blocks x 4096 edges.
// Per-block LDS histogram over buckets -> one global cursor atomic per
// (block,bucket) reserves a contiguous range -> packed writes in ~84B runs.
// pack = (local_node << 16) | col   (node<65536, col<65536)
// ---------------------------------------------------------------------------
__global__ __launch_bounds__(1024) void bucket_scatter_kernel(
        const int* __restrict__ row, const int* __restrict__ col,
        int* __restrict__ bucket_cursor, uint32_t* __restrict__ staged) {
    __shared__ int hist[NBUCK];
    __shared__ int hbase[NBUCK];
    int tid  = threadIdx.x;
    int e0   = blockIdx.x * EDGES_PER_BLK;
    int eend = e0 + EDGES_PER_BLK; if (eend > N_EDGES) eend = N_EDGES;

    for (int i = tid; i < NBUCK; i += 1024) hist[i] = 0;
    __syncthreads();

    int rr[4], cc[4]; int ne = 0;
    for (int e = e0 + tid; e < eend; e += 1024) {
        rr[ne] = row[e]; cc[ne] = col[e]; ne++;
    }
    for (int i = 0; i < ne; i++) atomicAdd(&hist[rr[i] >> 8], 1);
    __syncthreads();

    for (int i = tid; i < NBUCK; i += 1024) {
        hbase[i] = atomicAdd(&bucket_cursor[i], hist[i]);
        hist[i]  = 0;
    }
    __syncthreads();

    for (int i = 0; i < ne; i++) {
        int b   = rr[i] >> 8;
        int off = atomicAdd(&hist[b], 1);
        int pos = hbase[b] + off;
        if (pos < BCAP)   // statistical safety clamp (>24 sigma)
            staged[(size_t)b * BCAP + pos] =
                ((uint32_t)(rr[i] & 255) << 16) | (uint32_t)cc[i];
    }
}

// ---------------------------------------------------------------------------
// CSR build phase 1.5: exclusive scan of the 196 bucket sizes. One block.
// ---------------------------------------------------------------------------
__global__ void bucket_scan_kernel(const int* __restrict__ bucket_cursor,
                                   int* __restrict__ bucket_base) {
    __shared__ int wt[4];
    int tid = threadIdx.x, lane = tid & 63, wid = tid >> 6;
    int v = (tid < NBUCK) ? bucket_cursor[tid] : 0;
    int s = v;
#pragma unroll
    for (int off = 1; off < 64; off <<= 1) {
        int t = __shfl_up(s, off, 64);
        if (lane >= off) s += t;
    }
    if (lane == 63) wt[wid] = s;
    __syncthreads();
    if (tid == 0) { int a = 0; for (int i = 0; i < 4; i++) { int t = wt[i]; wt[i] = a; a += t; } }
    __syncthreads();
    if (tid < NBUCK) bucket_base[tid] = s - v + wt[wid];
}

// ---------------------------------------------------------------------------
// CSR build phase 2: one block per bucket. Count per local node in LDS,
// block-scan 256 counters, emit deg/rowstart/inv_deg coalesced, bin cols
// into LDS seg, flush csr_col coalesced. Replaces deg+scan1/2/3+fill.
// ---------------------------------------------------------------------------
__global__ __launch_bounds__(1024) void bucket_fill_kernel(
        const uint32_t* __restrict__ staged, const int* __restrict__ bucket_cursor,
        const int* __restrict__ bucket_base, int* __restrict__ deg,
        int* __restrict__ rowstart, float* __restrict__ inv_deg,
        int* __restrict__ csr_col) {
    __shared__ int cnt[256];
    __shared__ int excl[256];
    __shared__ int wt[4];
    __shared__ int seg[BCAP];
    int b   = blockIdx.x;
    int tid = threadIdx.x;
    int total = bucket_cursor[b]; if (total > BCAP) total = BCAP;
    int gbase = bucket_base[b];
    const uint32_t* st = staged + (size_t)b * BCAP;

    if (tid < 256) cnt[tid] = 0;
    __syncthreads();
    for (int i = tid; i < total; i += 1024) atomicAdd(&cnt[st[i] >> 16], 1);
    __syncthreads();

    int lane = tid & 63, wid = tid >> 6;
    int v = 0, s = 0;
    if (tid < 256) {
        v = cnt[tid]; s = v;
#pragma unroll
        for (int off = 1; off < 64; off <<= 1) {
            int t = __shfl_up(s, off, 64);
            if (lane >= off) s += t;
        }
        if (lane == 63) wt[wid] = s;
    }
    __syncthreads();
    if (tid == 0) { int a = 0; for (int i = 0; i < 4; i++) { int t = wt[i]; wt[i] = a; a += t; } }
    __syncthreads();
    if (tid < 256) {
        int ex = s - v + wt[wid];
        excl[tid] = ex;
        int node = (b << 8) + tid;
        if (node < N_NODES) {
            deg[node]      = v;
            rowstart[node] = gbase + ex;
            inv_deg[node]  = 1.0f / fmaxf((float)v, 1.0f);
        }
    }
    __syncthreads();
    for (int i = tid; i < total; i += 1024) {
        uint32_t u = st[i];
        int p = atomicAdd(&excl[u >> 16], 1);
        seg[p] = (int)(u & 0xffffu);
    }
    __syncthreads();
    for (int i = tid; i < total; i += 1024) csr_col[gbase + i] = seg[i];
}

// ---------------------------------------------------------------------------
// x (fp32) -> bf16
// ---------------------------------------------------------------------------
__global__ __launch_bounds__(256) void xcast_kernel(
        const float* __restrict__ x, __hip_bfloat16* __restrict__ xb) {
    size_t i = (size_t)(blockIdx.x * blockDim.x + threadIdx.x) * 4;
    if (i >= (size_t)N_NODES * D_FEAT) return;
    float4 v = *(const float4*)(x + i);
    uint2 p;
    p.x = (uint32_t)f2bf_bits(v.x) | ((uint32_t)f2bf_bits(v.y) << 16);
    p.y = (uint32_t)f2bf_bits(v.z) | ((uint32_t)f2bf_bits(v.w) << 16);
    *(uint2*)((uint16_t*)xb + i) = p;
}

// ---------------------------------------------------------------------------
// Pack all weights to bf16 in MFMA B-fragment order.
//   pack[((ns*ksteps + ks)*64 + l)*8 + j] = W[ks*32 + (l>>4)*8 + j][ns*16 + (l&15)]
// ---------------------------------------------------------------------------
__global__ __launch_bounds__(256) void pack_all_kernel(
        const float* __restrict__ selfk, const float* __restrict__ nbrk,
        const float* __restrict__ w1, const float* __restrict__ w2,
        __hip_bfloat16* __restrict__ wpack) {
    int m = blockIdx.y;
    const float* W; int K, Ncols, Npad; size_t dstoff;
    if (m < 3)      { W = selfk + (size_t)m*D_FEAT*HALF;      K=128; Ncols=64;  Npad=64;  dstoff = PK_SELF(m); }
    else if (m < 6) { W = nbrk  + (size_t)(m-3)*D_FEAT*HALF;  K=128; Ncols=64;  Npad=64;  dstoff = PK_NBR(m-3); }
    else if (m == 6){ W = w1;                                 K=128; Ncols=256; Npad=256; dstoff = PK_W1; }
    else            { W = w2;                                 K=256; Ncols=40;  Npad=48;  dstoff = PK_W2; }
    int ksteps = K / 32;
    int total  = ksteps * (Npad / 16) * 64;
    int t = blockIdx.x * blockDim.x + threadIdx.x;
    if (t >= total) return;
    int lane = t & 63;
    int rest = t >> 6;
    int ks   = rest % ksteps;
    int ns   = rest / ksteps;
    int colb = ns * 16 + (lane & 15);
    int kb   = ks * 32 + (lane >> 4) * 8;
    __hip_bfloat16* dst = wpack + dstoff + (size_t)t * 8;
#pragma unroll
    for (int j = 0; j < 8; j++) {
        float v = (colb < Ncols) ? W[(size_t)(kb + j) * Ncols + colb] : 0.f;
        dst[j] = __float2bfloat16(v);
    }
}

// ---------------------------------------------------------------------------
// Mean-neighbor aggregation (bf16): one wave per node, 4B (2 bf16) per lane.
// ---------------------------------------------------------------------------
__global__ __launch_bounds__(256) void agg_kernel(
        const __hip_bfloat16* __restrict__ h, const int* __restrict__ csr_col,
        const int* __restrict__ rowstart, const int* __restrict__ deg,
        const float* __restrict__ inv_deg, __hip_bfloat16* __restrict__ nbr) {
    int gid  = blockIdx.x * blockDim.x + threadIdx.x;
    int node = gid >> 6;
    int lane = threadIdx.x & 63;
    if (node >= N_NODES) return;
    int start = rowstart[node];
    int d     = deg[node];
    const uint32_t* hw = (const uint32_t*)h;   // row = 64 dwords
    float a0 = 0.f, a1 = 0.f;
    int j = 0;
    for (; j + 4 <= d; j += 4) {
        int s0 = csr_col[start + j + 0];
        int s1 = csr_col[start + j + 1];
        int s2 = csr_col[start + j + 2];
        int s3 = csr_col[start + j + 3];
        uint32_t u0 = hw[(size_t)s0 * 64 + lane];
        uint32_t u1 = hw[(size_t)s1 * 64 + lane];
        uint32_t u2 = hw[(size_t)s2 * 64 + lane];
        uint32_t u3 = hw[(size_t)s3 * 64 + lane];
        a0 += __uint_as_float(u0 << 16) + __uint_as_float(u1 << 16)
            + __uint_as_float(u2 << 16) + __uint_as_float(u3 << 16);
        a1 += __uint_as_float(u0 & 0xffff0000u) + __uint_as_float(u1 & 0xffff0000u)
            + __uint_as_float(u2 & 0xffff0000u) + __uint_as_float(u3 & 0xffff0000u);
    }
    for (; j < d; ++j) {
        int s = csr_col[start + j];
        uint32_t u = hw[(size_t)s * 64 + lane];
        a0 += __uint_as_float(u << 16);
        a1 += __uint_as_float(u & 0xffff0000u);
    }
    float inv = inv_deg[node];
    uint32_t pv = (uint32_t)f2bf_bits(a0 * inv) | ((uint32_t)f2bf_bits(a1 * inv) << 16);
    ((uint32_t*)nbr)[(size_t)node * 64 + lane] = pv;
}

// ---------------------------------------------------------------------------
// Layer GEMM (MFMA): out[N,128] = relu([h@Wself | nbr@Wnbr] + bias), bf16 out.
// ---------------------------------------------------------------------------
__global__ __launch_bounds__(256) void layer_mfma_kernel(
        const __hip_bfloat16* __restrict__ h, const __hip_bfloat16* __restrict__ nbr,
        const __hip_bfloat16* __restrict__ wpack_self,
        const __hip_bfloat16* __restrict__ wpack_nbr,
        const float* __restrict__ bias, __hip_bfloat16* __restrict__ out) {
    int wave = threadIdx.x >> 6, lane = threadIdx.x & 63;
    int half = wave >> 1;                       // 0: self(h), 1: nbr
    int row0 = blockIdx.x * 32 + (wave & 1) * 16;
    if (row0 >= N_NODES) return;
    int lrow = lane & 15, lgrp = lane >> 4;
    const __hip_bfloat16* A  = half ? nbr : h;
    const __hip_bfloat16* wp = half ? wpack_nbr : wpack_self;
    const __hip_bfloat16* arow = A + (size_t)(row0 + lrow) * D_FEAT + lgrp * 8;

    f32x4 acc[4] = {};
    for (int ks = 0; ks < 4; ks++) {
        bf16x8 af = *(const bf16x8*)(arow + ks * 32);
#pragma unroll
        for (int ns = 0; ns < 4; ns++) {
            bf16x8 bfr = *(const bf16x8*)(wp + ((size_t)(ns * 4 + ks) * 64 + lane) * 8);
            acc[ns] = __builtin_amdgcn_mfma_f32_16x16x32_bf16(af, bfr, acc[ns], 0, 0, 0);
        }
    }
    int colbase = half * 64;
#pragma unroll
    for (int ns = 0; ns < 4; ns++) {
        int col = colbase + ns * 16 + lrow;
        float bv = bias[col];
#pragma unroll
        for (int i = 0; i < 4; i++) {
            int r = row0 + lgrp * 4 + i;
            float v = fmaxf(acc[ns][i] + bv, 0.f);
            out[(size_t)r * D_FEAT + col] = __float2bfloat16(v);
        }
    }
}

// ---------------------------------------------------------------------------
// MLP1 (MFMA): hidden[N,256] = relu(h @ W1 + b1), bf16 out. Wave = 16 rows.
// ---------------------------------------------------------------------------
__global__ __launch_bounds__(256) void mlp1_mfma_kernel(
        const __hip_bfloat16* __restrict__ h, const __hip_bfloat16* __restrict__ w1p,
        const float* __restrict__ b1, __hip_bfloat16* __restrict__ hidden) {
    int wave = threadIdx.x >> 6, lane = threadIdx.x & 63;
    int row0 = blockIdx.x * 64 + wave * 16;
    if (row0 >= N_NODES) return;
    int lrow = lane & 15, lgrp = lane >> 4;
    const __hip_bfloat16* arow = h + (size_t)(row0 + lrow) * D_FEAT + lgrp * 8;

    f32x4 acc[16] = {};
    for (int ks = 0; ks < 4; ks++) {
        bf16x8 af = *(const bf16x8*)(arow + ks * 32);
#pragma unroll
        for (int ns = 0; ns < 16; ns++) {
            bf16x8 bfr = *(const bf16x8*)(w1p + ((size_t)(ns * 4 + ks) * 64 + lane) * 8);
            acc[ns] = __builtin_amdgcn_mfma_f32_16x16x32_bf16(af, bfr, acc[ns], 0, 0, 0);
        }
    }
#pragma unroll
    for (int ns = 0; ns < 16; ns++) {
        int col = ns * 16 + lrow;
        float bv = b1[col];
#pragma unroll
        for (int i = 0; i < 4; i++) {
            int r = row0 + lgrp * 4 + i;
            float v = fmaxf(acc[ns][i] + bv, 0.f);
            hidden[(size_t)r * HIDDEN + col] = __float2bfloat16(v);
        }
    }
}

// ---------------------------------------------------------------------------
// MLP2 (MFMA): out[N,40] = hidden @ W2 + b2 (fp32 out, N padded 40->48).
// ---------------------------------------------------------------------------
__global__ __launch_bounds__(256) void mlp2_mfma_kernel(
        const __hip_bfloat16* __restrict__ hidden, const __hip_bfloat16* __restrict__ w2p,
        const float* __restrict__ b2, float* __restrict__ out) {
    int wave = threadIdx.x >> 6, lane = threadIdx.x & 63;
    int row0 = blockIdx.x * 64 + wave * 16;
    if (row0 >= N_NODES) return;
    int lrow = lane & 15, lgrp = lane >> 4;
    const __hip_bfloat16* arow = hidden + (size_t)(row0 + lrow) * HIDDEN + lgrp * 8;

    f32x4 acc[3] = {};
    for (int ks = 0; ks < 8; ks++) {
        bf16x8 af = *(const bf16x8*)(arow + ks * 32);
#pragma unroll
        for (int ns = 0; ns < 3; ns++) {
            bf16x8 bfr = *(const bf16x8*)(w2p + ((size_t)(ns * 8 + ks) * 64 + lane) * 8);
            acc[ns] = __builtin_amdgcn_mfma_f32_16x16x32_bf16(af, bfr, acc[ns], 0, 0, 0);
        }
    }
#pragma unroll
    for (int ns = 0; ns < 3; ns++) {
        int col = ns * 16 + lrow;
        if (col < LABELS) {
            float bv = b2[col];
#pragma unroll
            for (int i = 0; i < 4; i++) {
                int r = row0 + lgrp * 4 + i;
                out[(size_t)r * LABELS + col] = acc[ns][i] + bv;
            }
        }
    }
}

// ---------------------------------------------------------------------------
extern "C" void kernel_launch(void* const* d_in, const int* in_sizes, int n_in,
                              void* d_out, int out_size, void* d_ws, size_t ws_size,
                              hipStream_t stream) {
    const float* x      = (const float*)d_in[0];
    const int*   ei     = (const int*)d_in[1];
    const float* selfk  = (const float*)d_in[2];
    const float* nbrk   = (const float*)d_in[3];
    const float* biases = (const float*)d_in[4];
    const float* w1     = (const float*)d_in[5];
    const float* b1     = (const float*)d_in[6];
    const float* w2     = (const float*)d_in[7];
    const float* b2     = (const float*)d_in[8];
    float* out = (float*)d_out;

    const int* row = ei;             // targets
    const int* col = ei + N_EDGES;   // sources

    char* ws = (char*)d_ws;
    size_t off = 0;
    auto alloc = [&](size_t bytes) -> char* {
        char* p = ws + off;
        off = (off + bytes + 255) & ~(size_t)255;
        return p;
    };
    int*   deg       = (int*)  alloc((size_t)N_NODES * 4);
    int*   rowstart  = (int*)  alloc((size_t)N_NODES * 4);
    float* inv_deg   = (float*)alloc((size_t)N_NODES * 4);
    int*   bucket_cursor = (int*)alloc(256 * 4);
    int*   bucket_base   = (int*)alloc(256 * 4);
    int*   csr_col   = (int*)  alloc((size_t)N_EDGES * 4);
    __hip_bfloat16* wpack  = (__hip_bfloat16*)alloc(PK_TOTAL * 2);
    __hip_bfloat16* xb     = (__hip_bfloat16*)alloc((size_t)N_NODES * D_FEAT * 2);
    __hip_bfloat16* hA     = (__hip_bfloat16*)alloc((size_t)N_NODES * D_FEAT * 2);
    __hip_bfloat16* hB     = (__hip_bfloat16*)alloc((size_t)N_NODES * D_FEAT * 2);
    __hip_bfloat16* nbrbuf = (__hip_bfloat16*)alloc((size_t)N_NODES * D_FEAT * 2);
    __hip_bfloat16* hidden = (__hip_bfloat16*)alloc((size_t)N_NODES * HIDDEN * 2);
    // staging (4.4 MB) aliases hidden (25.6 MB): dead before mlp1 writes hidden.
    uint32_t* staged = (uint32_t*)hidden;

    hipMemsetAsync(bucket_cursor, 0, 256 * 4, stream);

    const int scat_blocks = (N_EDGES + EDGES_PER_BLK - 1) / EDGES_PER_BLK;  // 196
    bucket_scatter_kernel<<<scat_blocks, 1024, 0, stream>>>(row, col, bucket_cursor, staged);
    bucket_scan_kernel<<<1, 256, 0, stream>>>(bucket_cursor, bucket_base);
    bucket_fill_kernel<<<NBUCK, 1024, 0, stream>>>(staged, bucket_cursor, bucket_base,
                                                   deg, rowstart, inv_deg, csr_col);

    xcast_kernel<<<(N_NODES * D_FEAT / 4 + 255) / 256, 256, 0, stream>>>(x, xb);
    dim3 pgrid(16, 8);
    pack_all_kernel<<<pgrid, 256, 0, stream>>>(selfk, nbrk, w1, w2, wpack);

    const int agg_blocks   = (N_NODES * 64 + 255) / 256;   // one wave per node
    const int layer_blocks = (N_NODES + 31) / 32;
    const int mlp_blocks   = (N_NODES + 63) / 64;

    const __hip_bfloat16* hcur = xb;
    __hip_bfloat16* bufs[3] = {hA, hB, hA};
    for (int L = 0; L < 3; L++) {
        agg_kernel<<<agg_blocks, 256, 0, stream>>>(hcur, csr_col, rowstart, deg,
                                                   inv_deg, nbrbuf);
        layer_mfma_kernel<<<layer_blocks, 256, 0, stream>>>(
            hcur, nbrbuf, wpack + PK_SELF(L), wpack + PK_NBR(L),
            biases + (size_t)L * (2 * HALF), bufs[L]);
        hcur = bufs[L];
    }

    mlp1_mfma_kernel<<<mlp_blocks, 256, 0, stream>>>(hcur, wpack + PK_W1, b1, hidden);
    mlp2_mfma_kernel<<<mlp_blocks, 256, 0, stream>>>(hidden, wpack + PK_W2, b2, out);
}

// Round 6
// 281.707 us; speedup vs baseline: 3.1213x; 1.0842x over previous
//
#include <hip/hip_runtime.h>
#include <hip/hip_bf16.h>
#include <cstdint>
#include <cstddef>

#define N_NODES 50000
#define N_PAD   50176    // padded rows for guard-free GEMM tiles
#define N_EDGES 800000
#define D_FEAT  128
#define HALF    64
#define HIDDEN  256
#define LABELS  40

#define NBUCK 196        // ceil(50000/256) buckets of 256 nodes (node>>8)
#define BCAP  5632       // staging cap per bucket; E[cnt]=4096, sigma~64 (24 sigma)
#define EDGES_PER_BLK 4096

typedef __attribute__((ext_vector_type(8))) short bf16x8;
typedef __attribute__((ext_vector_type(4))) float f32x4;

// Packed-weight layout offsets (in bf16 elements).
#define PK_SELF(L) ((size_t)(L) * 8192)
#define PK_NBR(L)  (24576 + (size_t)(L) * 8192)
#define PK_W1      49152
#define PK_W2      81920
#define PK_TOTAL   94208

__device__ inline uint16_t f2bf_bits(float f) {
    __hip_bfloat16 b = __float2bfloat16(f);
    uint16_t u; __builtin_memcpy(&u, &b, 2); return u;
}

// ---------------------------------------------------------------------------
// CSR build phase 1: bucket scatter. 196 blocks x 4096 edges.
// ---------------------------------------------------------------------------
__global__ __launch_bounds__(1024) void bucket_scatter_kernel(
        const int* __restrict__ row, const int* __restrict__ col,
        int* __restrict__ bucket_cursor, uint32_t* __restrict__ staged) {
    __shared__ int hist[NBUCK];
    __shared__ int hbase[NBUCK];
    int tid  = threadIdx.x;
    int e0   = blockIdx.x * EDGES_PER_BLK;
    int eend = e0 + EDGES_PER_BLK; if (eend > N_EDGES) eend = N_EDGES;

    for (int i = tid; i < NBUCK; i += 1024) hist[i] = 0;
    __syncthreads();

    int rr[4], cc[4]; int ne = 0;
    for (int e = e0 + tid; e < eend; e += 1024) {
        rr[ne] = row[e]; cc[ne] = col[e]; ne++;
    }
    for (int i = 0; i < ne; i++) atomicAdd(&hist[rr[i] >> 8], 1);
    __syncthreads();

    for (int i = tid; i < NBUCK; i += 1024) {
        hbase[i] = atomicAdd(&bucket_cursor[i], hist[i]);
        hist[i]  = 0;
    }
    __syncthreads();

    for (int i = 0; i < ne; i++) {
        int b   = rr[i] >> 8;
        int off = atomicAdd(&hist[b], 1);
        int pos = hbase[b] + off;
        if (pos < BCAP)
            staged[(size_t)b * BCAP + pos] =
                ((uint32_t)(rr[i] & 255) << 16) | (uint32_t)cc[i];
    }
}

// ---------------------------------------------------------------------------
// CSR build phase 1.5: exclusive scan of the 196 bucket sizes. One block.
// ---------------------------------------------------------------------------
__global__ void bucket_scan_kernel(const int* __restrict__ bucket_cursor,
                                   int* __restrict__ bucket_base) {
    __shared__ int wt[4];
    int tid = threadIdx.x, lane = tid & 63, wid = tid >> 6;
    int v = (tid < NBUCK) ? bucket_cursor[tid] : 0;
    int s = v;
#pragma unroll
    for (int off = 1; off < 64; off <<= 1) {
        int t = __shfl_up(s, off, 64);
        if (lane >= off) s += t;
    }
    if (lane == 63) wt[wid] = s;
    __syncthreads();
    if (tid == 0) { int a = 0; for (int i = 0; i < 4; i++) { int t = wt[i]; wt[i] = a; a += t; } }
    __syncthreads();
    if (tid < NBUCK) bucket_base[tid] = s - v + wt[wid];
}

// ---------------------------------------------------------------------------
// CSR build phase 2: one block per bucket -> deg/rowstart/inv_deg/csr_col.
// ---------------------------------------------------------------------------
__global__ __launch_bounds__(1024) void bucket_fill_kernel(
        const uint32_t* __restrict__ staged, const int* __restrict__ bucket_cursor,
        const int* __restrict__ bucket_base, int* __restrict__ deg,
        int* __restrict__ rowstart, float* __restrict__ inv_deg,
        int* __restrict__ csr_col) {
    __shared__ int cnt[256];
    __shared__ int excl[256];
    __shared__ int wt[4];
    __shared__ int seg[BCAP];
    int b   = blockIdx.x;
    int tid = threadIdx.x;
    int total = bucket_cursor[b]; if (total > BCAP) total = BCAP;
    int gbase = bucket_base[b];
    const uint32_t* st = staged + (size_t)b * BCAP;

    if (tid < 256) cnt[tid] = 0;
    __syncthreads();
    for (int i = tid; i < total; i += 1024) atomicAdd(&cnt[st[i] >> 16], 1);
    __syncthreads();

    int lane = tid & 63, wid = tid >> 6;
    int v = 0, s = 0;
    if (tid < 256) {
        v = cnt[tid]; s = v;
#pragma unroll
        for (int off = 1; off < 64; off <<= 1) {
            int t = __shfl_up(s, off, 64);
            if (lane >= off) s += t;
        }
        if (lane == 63) wt[wid] = s;
    }
    __syncthreads();
    if (tid == 0) { int a = 0; for (int i = 0; i < 4; i++) { int t = wt[i]; wt[i] = a; a += t; } }
    __syncthreads();
    if (tid < 256) {
        int ex = s - v + wt[wid];
        excl[tid] = ex;
        int node = (b << 8) + tid;
        if (node < N_NODES) {
            deg[node]      = v;
            rowstart[node] = gbase + ex;
            inv_deg[node]  = 1.0f / fmaxf((float)v, 1.0f);
        }
    }
    __syncthreads();
    for (int i = tid; i < total; i += 1024) {
        uint32_t u = st[i];
        int p = atomicAdd(&excl[u >> 16], 1);
        seg[p] = (int)(u & 0xffffu);
    }
    __syncthreads();
    for (int i = tid; i < total; i += 1024) csr_col[gbase + i] = seg[i];
}

// ---------------------------------------------------------------------------
// x (fp32) -> bf16
// ---------------------------------------------------------------------------
__global__ __launch_bounds__(256) void xcast_kernel(
        const float* __restrict__ x, __hip_bfloat16* __restrict__ xb) {
    size_t i = (size_t)(blockIdx.x * blockDim.x + threadIdx.x) * 4;
    if (i >= (size_t)N_NODES * D_FEAT) return;
    float4 v = *(const float4*)(x + i);
    uint2 p;
    p.x = (uint32_t)f2bf_bits(v.x) | ((uint32_t)f2bf_bits(v.y) << 16);
    p.y = (uint32_t)f2bf_bits(v.z) | ((uint32_t)f2bf_bits(v.w) << 16);
    *(uint2*)((uint16_t*)xb + i) = p;
}

// ---------------------------------------------------------------------------
// Pack all weights to bf16 in MFMA B-fragment order.
//   pack[((ns*ksteps + ks)*64 + l)*8 + j] = W[ks*32 + (l>>4)*8 + j][ns*16 + (l&15)]
// ---------------------------------------------------------------------------
__global__ __launch_bounds__(256) void pack_all_kernel(
        const float* __restrict__ selfk, const float* __restrict__ nbrk,
        const float* __restrict__ w1, const float* __restrict__ w2,
        __hip_bfloat16* __restrict__ wpack) {
    int m = blockIdx.y;
    const float* W; int K, Ncols, Npad; size_t dstoff;
    if (m < 3)      { W = selfk + (size_t)m*D_FEAT*HALF;      K=128; Ncols=64;  Npad=64;  dstoff = PK_SELF(m); }
    else if (m < 6) { W = nbrk  + (size_t)(m-3)*D_FEAT*HALF;  K=128; Ncols=64;  Npad=64;  dstoff = PK_NBR(m-3); }
    else if (m == 6){ W = w1;                                 K=128; Ncols=256; Npad=256; dstoff = PK_W1; }
    else            { W = w2;                                 K=256; Ncols=40;  Npad=48;  dstoff = PK_W2; }
    int ksteps = K / 32;
    int total  = ksteps * (Npad / 16) * 64;
    int t = blockIdx.x * blockDim.x + threadIdx.x;
    if (t >= total) return;
    int lane = t & 63;
    int rest = t >> 6;
    int ks   = rest % ksteps;
    int ns   = rest / ksteps;
    int colb = ns * 16 + (lane & 15);
    int kb   = ks * 32 + (lane >> 4) * 8;
    __hip_bfloat16* dst = wpack + dstoff + (size_t)t * 8;
#pragma unroll
    for (int j = 0; j < 8; j++) {
        float v = (colb < Ncols) ? W[(size_t)(kb + j) * Ncols + colb] : 0.f;
        dst[j] = __float2bfloat16(v);
    }
}

// ---------------------------------------------------------------------------
// Mean-neighbor aggregation (bf16): one wave per node, 4B (2 bf16) per lane.
// ---------------------------------------------------------------------------
__global__ __launch_bounds__(256) void agg_kernel(
        const __hip_bfloat16* __restrict__ h, const int* __restrict__ csr_col,
        const int* __restrict__ rowstart, const int* __restrict__ deg,
        const float* __restrict__ inv_deg, __hip_bfloat16* __restrict__ nbr) {
    int gid  = blockIdx.x * blockDim.x + threadIdx.x;
    int node = gid >> 6;
    int lane = threadIdx.x & 63;
    if (node >= N_NODES) return;
    int start = rowstart[node];
    int d     = deg[node];
    const uint32_t* hw = (const uint32_t*)h;   // row = 64 dwords
    float a0 = 0.f, a1 = 0.f;
    int j = 0;
    for (; j + 4 <= d; j += 4) {
        int s0 = csr_col[start + j + 0];
        int s1 = csr_col[start + j + 1];
        int s2 = csr_col[start + j + 2];
        int s3 = csr_col[start + j + 3];
        uint32_t u0 = hw[(size_t)s0 * 64 + lane];
        uint32_t u1 = hw[(size_t)s1 * 64 + lane];
        uint32_t u2 = hw[(size_t)s2 * 64 + lane];
        uint32_t u3 = hw[(size_t)s3 * 64 + lane];
        a0 += __uint_as_float(u0 << 16) + __uint_as_float(u1 << 16)
            + __uint_as_float(u2 << 16) + __uint_as_float(u3 << 16);
        a1 += __uint_as_float(u0 & 0xffff0000u) + __uint_as_float(u1 & 0xffff0000u)
            + __uint_as_float(u2 & 0xffff0000u) + __uint_as_float(u3 & 0xffff0000u);
    }
    for (; j < d; ++j) {
        int s = csr_col[start + j];
        uint32_t u = hw[(size_t)s * 64 + lane];
        a0 += __uint_as_float(u << 16);
        a1 += __uint_as_float(u & 0xffff0000u);
    }
    float inv = inv_deg[node];
    uint32_t pv = (uint32_t)f2bf_bits(a0 * inv) | ((uint32_t)f2bf_bits(a1 * inv) << 16);
    ((uint32_t*)nbr)[(size_t)node * 64 + lane] = pv;
}

// ---------------------------------------------------------------------------
// Layer GEMM (MFMA): out[N,128] = relu([h@Wself | nbr@Wnbr] + bias), bf16 out.
// 32 rows/wave (2 A-frags share each B-frag). launch_bounds(256,2): VGPR cap
// 256 so all B-frags stay in flight (68-VGPR alloc serialized loads in r5).
// ---------------------------------------------------------------------------
__global__ __launch_bounds__(256, 2) void layer_mfma_kernel(
        const __hip_bfloat16* __restrict__ h, const __hip_bfloat16* __restrict__ nbr,
        const __hip_bfloat16* __restrict__ wpack_self,
        const __hip_bfloat16* __restrict__ wpack_nbr,
        const float* __restrict__ bias, __hip_bfloat16* __restrict__ out) {
    int wave = threadIdx.x >> 6, lane = threadIdx.x & 63;
    int half = wave >> 1;                       // 0: self(h), 1: nbr
    int row0 = blockIdx.x * 64 + (wave & 1) * 32;
    int lrow = lane & 15, lgrp = lane >> 4;
    const __hip_bfloat16* A  = half ? nbr : h;
    const __hip_bfloat16* wp = half ? wpack_nbr : wpack_self;
    const __hip_bfloat16* ar0 = A + (size_t)(row0 + lrow) * D_FEAT + lgrp * 8;
    const __hip_bfloat16* ar1 = ar0 + (size_t)16 * D_FEAT;

    f32x4 acc[2][4] = {};
#pragma unroll
    for (int ks = 0; ks < 4; ks++) {
        bf16x8 a0 = *(const bf16x8*)(ar0 + ks * 32);
        bf16x8 a1 = *(const bf16x8*)(ar1 + ks * 32);
#pragma unroll
        for (int ns = 0; ns < 4; ns++) {
            bf16x8 bfr = *(const bf16x8*)(wp + ((size_t)(ns * 4 + ks) * 64 + lane) * 8);
            acc[0][ns] = __builtin_amdgcn_mfma_f32_16x16x32_bf16(a0, bfr, acc[0][ns], 0, 0, 0);
            acc[1][ns] = __builtin_amdgcn_mfma_f32_16x16x32_bf16(a1, bfr, acc[1][ns], 0, 0, 0);
        }
    }
    int colbase = half * 64;
#pragma unroll
    for (int t = 0; t < 2; t++) {
#pragma unroll
        for (int ns = 0; ns < 4; ns++) {
            int col = colbase + ns * 16 + lrow;
            float bv = bias[col];
#pragma unroll
            for (int i = 0; i < 4; i++) {
                int r = row0 + t * 16 + lgrp * 4 + i;     // < N_PAD, unguarded
                out[(size_t)r * D_FEAT + col] =
                    __float2bfloat16(fmaxf(acc[t][ns][i] + bv, 0.f));
            }
        }
    }
}

// ---------------------------------------------------------------------------
// MLP1 (MFMA): hidden[N,256] = relu(h @ W1 + b1), bf16 out. 32 rows/wave.
// ---------------------------------------------------------------------------
__global__ __launch_bounds__(256, 2) void mlp1_mfma_kernel(
        const __hip_bfloat16* __restrict__ h, const __hip_bfloat16* __restrict__ w1p,
        const float* __restrict__ b1, __hip_bfloat16* __restrict__ hidden) {
    int wave = threadIdx.x >> 6, lane = threadIdx.x & 63;
    int row0 = blockIdx.x * 128 + wave * 32;
    int lrow = lane & 15, lgrp = lane >> 4;
    const __hip_bfloat16* ar0 = h + (size_t)(row0 + lrow) * D_FEAT + lgrp * 8;
    const __hip_bfloat16* ar1 = ar0 + (size_t)16 * D_FEAT;

    f32x4 acc[2][16] = {};
#pragma unroll 1
    for (int ks = 0; ks < 4; ks++) {
        bf16x8 a0 = *(const bf16x8*)(ar0 + ks * 32);
        bf16x8 a1 = *(const bf16x8*)(ar1 + ks * 32);
#pragma unroll
        for (int ns = 0; ns < 16; ns++) {
            bf16x8 bfr = *(const bf16x8*)(w1p + ((size_t)(ns * 4 + ks) * 64 + lane) * 8);
            acc[0][ns] = __builtin_amdgcn_mfma_f32_16x16x32_bf16(a0, bfr, acc[0][ns], 0, 0, 0);
            acc[1][ns] = __builtin_amdgcn_mfma_f32_16x16x32_bf16(a1, bfr, acc[1][ns], 0, 0, 0);
        }
    }
#pragma unroll
    for (int t = 0; t < 2; t++) {
#pragma unroll
        for (int ns = 0; ns < 16; ns++) {
            int col = ns * 16 + lrow;
            float bv = b1[col];
#pragma unroll
            for (int i = 0; i < 4; i++) {
                int r = row0 + t * 16 + lgrp * 4 + i;     // < N_PAD, unguarded
                hidden[(size_t)r * HIDDEN + col] =
                    __float2bfloat16(fmaxf(acc[t][ns][i] + bv, 0.f));
            }
        }
    }
}

// ---------------------------------------------------------------------------
// MLP2 (MFMA): out[N,40] = hidden @ W2 + b2 (fp32 out). 32 rows/wave.
// ---------------------------------------------------------------------------
__global__ __launch_bounds__(256, 2) void mlp2_mfma_kernel(
        const __hip_bfloat16* __restrict__ hidden, const __hip_bfloat16* __restrict__ w2p,
        const float* __restrict__ b2, float* __restrict__ out) {
    int wave = threadIdx.x >> 6, lane = threadIdx.x & 63;
    int row0 = blockIdx.x * 128 + wave * 32;
    int lrow = lane & 15, lgrp = lane >> 4;
    const __hip_bfloat16* ar0 = hidden + (size_t)(row0 + lrow) * HIDDEN + lgrp * 8;
    const __hip_bfloat16* ar1 = ar0 + (size_t)16 * HIDDEN;

    f32x4 acc[2][3] = {};
#pragma unroll
    for (int ks = 0; ks < 8; ks++) {
        bf16x8 a0 = *(const bf16x8*)(ar0 + ks * 32);
        bf16x8 a1 = *(const bf16x8*)(ar1 + ks * 32);
#pragma unroll
        for (int ns = 0; ns < 3; ns++) {
            bf16x8 bfr = *(const bf16x8*)(w2p + ((size_t)(ns * 8 + ks) * 64 + lane) * 8);
            acc[0][ns] = __builtin_amdgcn_mfma_f32_16x16x32_bf16(a0, bfr, acc[0][ns], 0, 0, 0);
            acc[1][ns] = __builtin_amdgcn_mfma_f32_16x16x32_bf16(a1, bfr, acc[1][ns], 0, 0, 0);
        }
    }
#pragma unroll
    for (int t = 0; t < 2; t++) {
#pragma unroll
        for (int ns = 0; ns < 3; ns++) {
            int col = ns * 16 + lrow;
            if (col < LABELS) {
                float bv = b2[col];
#pragma unroll
                for (int i = 0; i < 4; i++) {
                    int r = row0 + t * 16 + lgrp * 4 + i;
                    if (r < N_NODES)                       // d_out: exact size
                        out[(size_t)r * LABELS + col] = acc[t][ns][i] + bv;
                }
            }
        }
    }
}

// ---------------------------------------------------------------------------
extern "C" void kernel_launch(void* const* d_in, const int* in_sizes, int n_in,
                              void* d_out, int out_size, void* d_ws, size_t ws_size,
                              hipStream_t stream) {
    const float* x      = (const float*)d_in[0];
    const int*   ei     = (const int*)d_in[1];
    const float* selfk  = (const float*)d_in[2];
    const float* nbrk   = (const float*)d_in[3];
    const float* biases = (const float*)d_in[4];
    const float* w1     = (const float*)d_in[5];
    const float* b1     = (const float*)d_in[6];
    const float* w2     = (const float*)d_in[7];
    const float* b2     = (const float*)d_in[8];
    float* out = (float*)d_out;

    const int* row = ei;             // targets
    const int* col = ei + N_EDGES;   // sources

    char* ws = (char*)d_ws;
    size_t off = 0;
    auto alloc = [&](size_t bytes) -> char* {
        char* p = ws + off;
        off = (off + bytes + 255) & ~(size_t)255;
        return p;
    };
    int*   deg       = (int*)  alloc((size_t)N_NODES * 4);
    int*   rowstart  = (int*)  alloc((size_t)N_NODES * 4);
    float* inv_deg   = (float*)alloc((size_t)N_NODES * 4);
    int*   bucket_cursor = (int*)alloc(256 * 4);
    int*   bucket_base   = (int*)alloc(256 * 4);
    int*   csr_col   = (int*)  alloc((size_t)N_EDGES * 4);
    __hip_bfloat16* wpack  = (__hip_bfloat16*)alloc(PK_TOTAL * 2);
    __hip_bfloat16* xb     = (__hip_bfloat16*)alloc((size_t)N_PAD * D_FEAT * 2);
    __hip_bfloat16* hA     = (__hip_bfloat16*)alloc((size_t)N_PAD * D_FEAT * 2);
    __hip_bfloat16* hB     = (__hip_bfloat16*)alloc((size_t)N_PAD * D_FEAT * 2);
    __hip_bfloat16* nbrbuf = (__hip_bfloat16*)alloc((size_t)N_PAD * D_FEAT * 2);
    __hip_bfloat16* hidden = (__hip_bfloat16*)alloc((size_t)N_PAD * HIDDEN * 2);
    // staging (4.4 MB) aliases hidden (25.7 MB): dead before mlp1 writes hidden.
    uint32_t* staged = (uint32_t*)hidden;

    hipMemsetAsync(bucket_cursor, 0, 256 * 4, stream);

    const int scat_blocks = (N_EDGES + EDGES_PER_BLK - 1) / EDGES_PER_BLK;  // 196
    bucket_scatter_kernel<<<scat_blocks, 1024, 0, stream>>>(row, col, bucket_cursor, staged);
    bucket_scan_kernel<<<1, 256, 0, stream>>>(bucket_cursor, bucket_base);
    bucket_fill_kernel<<<NBUCK, 1024, 0, stream>>>(staged, bucket_cursor, bucket_base,
                                                   deg, rowstart, inv_deg, csr_col);

    xcast_kernel<<<(N_NODES * D_FEAT / 4 + 255) / 256, 256, 0, stream>>>(x, xb);
    dim3 pgrid(16, 8);
    pack_all_kernel<<<pgrid, 256, 0, stream>>>(selfk, nbrk, w1, w2, wpack);

    const int agg_blocks   = (N_NODES * 64 + 255) / 256;   // one wave per node
    const int layer_blocks = (N_NODES + 63) / 64;          // 64 rows/block
    const int mlp_blocks   = (N_NODES + 127) / 128;        // 128 rows/block

    const __hip_bfloat16* hcur = xb;
    __hip_bfloat16* bufs[3] = {hA, hB, hA};
    for (int L = 0; L < 3; L++) {
        agg_kernel<<<agg_blocks, 256, 0, stream>>>(hcur, csr_col, rowstart, deg,
                                                   inv_deg, nbrbuf);
        layer_mfma_kernel<<<layer_blocks, 256, 0, stream>>>(
            hcur, nbrbuf, wpack + PK_SELF(L), wpack + PK_NBR(L),
            biases + (size_t)L * (2 * HALF), bufs[L]);
        hcur = bufs[L];
    }

    mlp1_mfma_kernel<<<mlp_blocks, 256, 0, stream>>>(hcur, wpack + PK_W1, b1, hidden);
    mlp2_mfma_kernel<<<mlp_blocks, 256, 0, stream>>>(hidden, wpack + PK_W2, b2, out);
}

// Round 8
// 279.957 us; speedup vs baseline: 3.1408x; 1.0063x over previous
//
#include <hip/hip_runtime.h>
#include <hip/hip_bf16.h>
#include <cstdint>
#include <cstddef>

#define N_NODES 50000
#define N_PAD   50176    // padded rows for guard-free GEMM tiles
#define N_EDGES 800000
#define D_FEAT  128
#define HALF    64
#define HIDDEN  256
#define LABELS  40

#define NBUCK 196        // ceil(50000/256) buckets of 256 nodes (node>>8)
#define BCAP  5632       // staging cap per bucket; E[cnt]=4096, sigma~64 (24 sigma)
#define EDGES_PER_BLK 4096

typedef __attribute__((ext_vector_type(8))) short bf16x8;
typedef __attribute__((ext_vector_type(4))) float f32x4;

// Packed-weight layout offsets (in bf16 elements).
#define PK_SELF(L) ((size_t)(L) * 8192)
#define PK_NBR(L)  (24576 + (size_t)(L) * 8192)
#define PK_W1      49152
#define PK_W2      81920
#define PK_TOTAL   94208

__device__ inline uint16_t f2bf_bits(float f) {
    __hip_bfloat16 b = __float2bfloat16(f);
    uint16_t u; __builtin_memcpy(&u, &b, 2); return u;
}

// ---------------------------------------------------------------------------
// CSR build phase 1: bucket scatter. 196 blocks x 4096 edges.
// ---------------------------------------------------------------------------
__global__ __launch_bounds__(1024) void bucket_scatter_kernel(
        const int* __restrict__ row, const int* __restrict__ col,
        int* __restrict__ bucket_cursor, uint32_t* __restrict__ staged) {
    __shared__ int hist[NBUCK];
    __shared__ int hbase[NBUCK];
    int tid  = threadIdx.x;
    int e0   = blockIdx.x * EDGES_PER_BLK;
    int eend = e0 + EDGES_PER_BLK; if (eend > N_EDGES) eend = N_EDGES;

    for (int i = tid; i < NBUCK; i += 1024) hist[i] = 0;
    __syncthreads();

    int rr[4], cc[4]; int ne = 0;
    for (int e = e0 + tid; e < eend; e += 1024) {
        rr[ne] = row[e]; cc[ne] = col[e]; ne++;
    }
    for (int i = 0; i < ne; i++) atomicAdd(&hist[rr[i] >> 8], 1);
    __syncthreads();

    for (int i = tid; i < NBUCK; i += 1024) {
        hbase[i] = atomicAdd(&bucket_cursor[i], hist[i]);
        hist[i]  = 0;
    }
    __syncthreads();

    for (int i = 0; i < ne; i++) {
        int b   = rr[i] >> 8;
        int off = atomicAdd(&hist[b], 1);
        int pos = hbase[b] + off;
        if (pos < BCAP)
            staged[(size_t)b * BCAP + pos] =
                ((uint32_t)(rr[i] & 255) << 16) | (uint32_t)cc[i];
    }
}

// ---------------------------------------------------------------------------
// CSR build phase 1.5: exclusive scan of the 196 bucket sizes. One block.
// ---------------------------------------------------------------------------
__global__ void bucket_scan_kernel(const int* __restrict__ bucket_cursor,
                                   int* __restrict__ bucket_base) {
    __shared__ int wt[4];
    int tid = threadIdx.x, lane = tid & 63, wid = tid >> 6;
    int v = (tid < NBUCK) ? bucket_cursor[tid] : 0;
    int s = v;
#pragma unroll
    for (int off = 1; off < 64; off <<= 1) {
        int t = __shfl_up(s, off, 64);
        if (lane >= off) s += t;
    }
    if (lane == 63) wt[wid] = s;
    __syncthreads();
    if (tid == 0) { int a = 0; for (int i = 0; i < 4; i++) { int t = wt[i]; wt[i] = a; a += t; } }
    __syncthreads();
    if (tid < NBUCK) bucket_base[tid] = s - v + wt[wid];
}

// ---------------------------------------------------------------------------
// CSR build phase 2: one block per bucket -> deg/rowstart/inv_deg/csr_col.
// ---------------------------------------------------------------------------
__global__ __launch_bounds__(1024) void bucket_fill_kernel(
        const uint32_t* __restrict__ staged, const int* __restrict__ bucket_cursor,
        const int* __restrict__ bucket_base, int* __restrict__ deg,
        int* __restrict__ rowstart, float* __restrict__ inv_deg,
        int* __restrict__ csr_col) {
    __shared__ int cnt[256];
    __shared__ int excl[256];
    __shared__ int wt[4];
    __shared__ int seg[BCAP];
    int b   = blockIdx.x;
    int tid = threadIdx.x;
    int total = bucket_cursor[b]; if (total > BCAP) total = BCAP;
    int gbase = bucket_base[b];
    const uint32_t* st = staged + (size_t)b * BCAP;

    if (tid < 256) cnt[tid] = 0;
    __syncthreads();
    for (int i = tid; i < total; i += 1024) atomicAdd(&cnt[st[i] >> 16], 1);
    __syncthreads();

    int lane = tid & 63, wid = tid >> 6;
    int v = 0, s = 0;
    if (tid < 256) {
        v = cnt[tid]; s = v;
#pragma unroll
        for (int off = 1; off < 64; off <<= 1) {
            int t = __shfl_up(s, off, 64);
            if (lane >= off) s += t;
        }
        if (lane == 63) wt[wid] = s;
    }
    __syncthreads();
    if (tid == 0) { int a = 0; for (int i = 0; i < 4; i++) { int t = wt[i]; wt[i] = a; a += t; } }
    __syncthreads();
    if (tid < 256) {
        int ex = s - v + wt[wid];
        excl[tid] = ex;
        int node = (b << 8) + tid;
        if (node < N_NODES) {
            deg[node]      = v;
            rowstart[node] = gbase + ex;
            inv_deg[node]  = 1.0f / fmaxf((float)v, 1.0f);
        }
    }
    __syncthreads();
    for (int i = tid; i < total; i += 1024) {
        uint32_t u = st[i];
        int p = atomicAdd(&excl[u >> 16], 1);
        seg[p] = (int)(u & 0xffffu);
    }
    __syncthreads();
    for (int i = tid; i < total; i += 1024) csr_col[gbase + i] = seg[i];
}

// ---------------------------------------------------------------------------
// x (fp32) -> bf16
// ---------------------------------------------------------------------------
__global__ __launch_bounds__(256) void xcast_kernel(
        const float* __restrict__ x, __hip_bfloat16* __restrict__ xb) {
    size_t i = (size_t)(blockIdx.x * blockDim.x + threadIdx.x) * 4;
    if (i >= (size_t)N_NODES * D_FEAT) return;
    float4 v = *(const float4*)(x + i);
    uint2 p;
    p.x = (uint32_t)f2bf_bits(v.x) | ((uint32_t)f2bf_bits(v.y) << 16);
    p.y = (uint32_t)f2bf_bits(v.z) | ((uint32_t)f2bf_bits(v.w) << 16);
    *(uint2*)((uint16_t*)xb + i) = p;
}

// ---------------------------------------------------------------------------
// Pack all weights to bf16 in MFMA B-fragment order.
//   pack[((ns*ksteps + ks)*64 + l)*8 + j] = W[ks*32 + (l>>4)*8 + j][ns*16 + (l&15)]
// ---------------------------------------------------------------------------
__global__ __launch_bounds__(256) void pack_all_kernel(
        const float* __restrict__ selfk, const float* __restrict__ nbrk,
        const float* __restrict__ w1, const float* __restrict__ w2,
        __hip_bfloat16* __restrict__ wpack) {
    int m = blockIdx.y;
    const float* W; int K, Ncols, Npad; size_t dstoff;
    if (m < 3)      { W = selfk + (size_t)m*D_FEAT*HALF;      K=128; Ncols=64;  Npad=64;  dstoff = PK_SELF(m); }
    else if (m < 6) { W = nbrk  + (size_t)(m-3)*D_FEAT*HALF;  K=128; Ncols=64;  Npad=64;  dstoff = PK_NBR(m-3); }
    else if (m == 6){ W = w1;                                 K=128; Ncols=256; Npad=256; dstoff = PK_W1; }
    else            { W = w2;                                 K=256; Ncols=40;  Npad=48;  dstoff = PK_W2; }
    int ksteps = K / 32;
    int total  = ksteps * (Npad / 16) * 64;
    int t = blockIdx.x * blockDim.x + threadIdx.x;
    if (t >= total) return;
    int lane = t & 63;
    int rest = t >> 6;
    int ks   = rest % ksteps;
    int ns   = rest / ksteps;
    int colb = ns * 16 + (lane & 15);
    int kb   = ks * 32 + (lane >> 4) * 8;
    __hip_bfloat16* dst = wpack + dstoff + (size_t)t * 8;
#pragma unroll
    for (int j = 0; j < 8; j++) {
        float v = (colb < Ncols) ? W[(size_t)(kb + j) * Ncols + colb] : 0.f;
        dst[j] = __float2bfloat16(v);
    }
}

// ---------------------------------------------------------------------------
// Mean-neighbor aggregation (bf16): TWO nodes per wave, 8B (4 bf16) per lane.
// 32 lanes cover a 256B row -> 32 loads/edge (vs 64 in the 1-node/wave form).
// Per-node summation order identical to the r6 kernel (bit-compatible).
// ---------------------------------------------------------------------------
__global__ __launch_bounds__(256) void agg2_kernel(
        const __hip_bfloat16* __restrict__ h, const int* __restrict__ csr_col,
        const int* __restrict__ rowstart, const int* __restrict__ deg,
        const float* __restrict__ inv_deg, __hip_bfloat16* __restrict__ nbr) {
    int gid  = blockIdx.x * blockDim.x + threadIdx.x;
    int wnum = gid >> 6;                 // wave index
    int lane = threadIdx.x & 63;
    int sub  = lane >> 5;                // which of the wave's 2 nodes
    int sl   = lane & 31;                // lane within node: dwords [2*sl, 2*sl+1]
    int node = wnum * 2 + sub;           // grid exact: node < 50000 always
    int start = rowstart[node];
    int d     = deg[node];
    const uint32_t* hw = (const uint32_t*)h;   // row = 64 dwords
    float a0 = 0.f, a1 = 0.f, a2 = 0.f, a3 = 0.f;
    int j = 0;
    for (; j + 2 <= d; j += 2) {
        int s0 = csr_col[start + j];
        int s1 = csr_col[start + j + 1];
        uint2 u0 = *(const uint2*)(hw + (size_t)s0 * 64 + sl * 2);
        uint2 u1 = *(const uint2*)(hw + (size_t)s1 * 64 + sl * 2);
        a0 += __uint_as_float(u0.x << 16);
        a1 += __uint_as_float(u0.x & 0xffff0000u);
        a2 += __uint_as_float(u0.y << 16);
        a3 += __uint_as_float(u0.y & 0xffff0000u);
        a0 += __uint_as_float(u1.x << 16);
        a1 += __uint_as_float(u1.x & 0xffff0000u);
        a2 += __uint_as_float(u1.y << 16);
        a3 += __uint_as_float(u1.y & 0xffff0000u);
    }
    if (j < d) {
        int s = csr_col[start + j];
        uint2 u = *(const uint2*)(hw + (size_t)s * 64 + sl * 2);
        a0 += __uint_as_float(u.x << 16);
        a1 += __uint_as_float(u.x & 0xffff0000u);
        a2 += __uint_as_float(u.y << 16);
        a3 += __uint_as_float(u.y & 0xffff0000u);
    }
    float inv = inv_deg[node];
    uint2 p;
    p.x = (uint32_t)f2bf_bits(a0 * inv) | ((uint32_t)f2bf_bits(a1 * inv) << 16);
    p.y = (uint32_t)f2bf_bits(a2 * inv) | ((uint32_t)f2bf_bits(a3 * inv) << 16);
    *(uint2*)((uint32_t*)nbr + (size_t)node * 64 + sl * 2) = p;
}

// ---------------------------------------------------------------------------
// Layer GEMM (MFMA): out[N,128] = relu([h@Wself | nbr@Wnbr] + bias), bf16 out.
// 32 rows/wave (2 A-frags share each B-frag). launch_bounds(256,2): VGPR cap
// 256 so all B-frags stay in flight (68-VGPR alloc serialized loads in r5).
// ---------------------------------------------------------------------------
__global__ __launch_bounds__(256, 2) void layer_mfma_kernel(
        const __hip_bfloat16* __restrict__ h, const __hip_bfloat16* __restrict__ nbr,
        const __hip_bfloat16* __restrict__ wpack_self,
        const __hip_bfloat16* __restrict__ wpack_nbr,
        const float* __restrict__ bias, __hip_bfloat16* __restrict__ out) {
    int wave = threadIdx.x >> 6, lane = threadIdx.x & 63;
    int half = wave >> 1;                       // 0: self(h), 1: nbr
    int row0 = blockIdx.x * 64 + (wave & 1) * 32;
    int lrow = lane & 15, lgrp = lane >> 4;
    const __hip_bfloat16* A  = half ? nbr : h;
    const __hip_bfloat16* wp = half ? wpack_nbr : wpack_self;
    const __hip_bfloat16* ar0 = A + (size_t)(row0 + lrow) * D_FEAT + lgrp * 8;
    const __hip_bfloat16* ar1 = ar0 + (size_t)16 * D_FEAT;

    f32x4 acc[2][4] = {};
#pragma unroll
    for (int ks = 0; ks < 4; ks++) {
        bf16x8 a0 = *(const bf16x8*)(ar0 + ks * 32);
        bf16x8 a1 = *(const bf16x8*)(ar1 + ks * 32);
#pragma unroll
        for (int ns = 0; ns < 4; ns++) {
            bf16x8 bfr = *(const bf16x8*)(wp + ((size_t)(ns * 4 + ks) * 64 + lane) * 8);
            acc[0][ns] = __builtin_amdgcn_mfma_f32_16x16x32_bf16(a0, bfr, acc[0][ns], 0, 0, 0);
            acc[1][ns] = __builtin_amdgcn_mfma_f32_16x16x32_bf16(a1, bfr, acc[1][ns], 0, 0, 0);
        }
    }
    int colbase = half * 64;
#pragma unroll
    for (int t = 0; t < 2; t++) {
#pragma unroll
        for (int ns = 0; ns < 4; ns++) {
            int col = colbase + ns * 16 + lrow;
            float bv = bias[col];
#pragma unroll
            for (int i = 0; i < 4; i++) {
                int r = row0 + t * 16 + lgrp * 4 + i;     // < N_PAD, unguarded
                out[(size_t)r * D_FEAT + col] =
                    __float2bfloat16(fmaxf(acc[t][ns][i] + bv, 0.f));
            }
        }
    }
}

// ---------------------------------------------------------------------------
// MLP1 (MFMA): hidden[N,256] = relu(h @ W1 + b1), bf16 out. 32 rows/wave.
// ---------------------------------------------------------------------------
__global__ __launch_bounds__(256, 2) void mlp1_mfma_kernel(
        const __hip_bfloat16* __restrict__ h, const __hip_bfloat16* __restrict__ w1p,
        const float* __restrict__ b1, __hip_bfloat16* __restrict__ hidden) {
    int wave = threadIdx.x >> 6, lane = threadIdx.x & 63;
    int row0 = blockIdx.x * 128 + wave * 32;
    int lrow = lane & 15, lgrp = lane >> 4;
    const __hip_bfloat16* ar0 = h + (size_t)(row0 + lrow) * D_FEAT + lgrp * 8;
    const __hip_bfloat16* ar1 = ar0 + (size_t)16 * D_FEAT;

    f32x4 acc[2][16] = {};
#pragma unroll 1
    for (int ks = 0; ks < 4; ks++) {
        bf16x8 a0 = *(const bf16x8*)(ar0 + ks * 32);
        bf16x8 a1 = *(const bf16x8*)(ar1 + ks * 32);
#pragma unroll
        for (int ns = 0; ns < 16; ns++) {
            bf16x8 bfr = *(const bf16x8*)(w1p + ((size_t)(ns * 4 + ks) * 64 + lane) * 8);
            acc[0][ns] = __builtin_amdgcn_mfma_f32_16x16x32_bf16(a0, bfr, acc[0][ns], 0, 0, 0);
            acc[1][ns] = __builtin_amdgcn_mfma_f32_16x16x32_bf16(a1, bfr, acc[1][ns], 0, 0, 0);
        }
    }
#pragma unroll
    for (int t = 0; t < 2; t++) {
#pragma unroll
        for (int ns = 0; ns < 16; ns++) {
            int col = ns * 16 + lrow;
            float bv = b1[col];
#pragma unroll
            for (int i = 0; i < 4; i++) {
                int r = row0 + t * 16 + lgrp * 4 + i;     // < N_PAD, unguarded
                hidden[(size_t)r * HIDDEN + col] =
                    __float2bfloat16(fmaxf(acc[t][ns][i] + bv, 0.f));
            }
        }
    }
}

// ---------------------------------------------------------------------------
// MLP2 (MFMA): out[N,40] = hidden @ W2 + b2 (fp32 out). 32 rows/wave.
// ---------------------------------------------------------------------------
__global__ __launch_bounds__(256, 2) void mlp2_mfma_kernel(
        const __hip_bfloat16* __restrict__ hidden, const __hip_bfloat16* __restrict__ w2p,
        const float* __restrict__ b2, float* __restrict__ out) {
    int wave = threadIdx.x >> 6, lane = threadIdx.x & 63;
    int row0 = blockIdx.x * 128 + wave * 32;
    int lrow = lane & 15, lgrp = lane >> 4;
    const __hip_bfloat16* ar0 = hidden + (size_t)(row0 + lrow) * HIDDEN + lgrp * 8;
    const __hip_bfloat16* ar1 = ar0 + (size_t)16 * HIDDEN;

    f32x4 acc[2][3] = {};
#pragma unroll
    for (int ks = 0; ks < 8; ks++) {
        bf16x8 a0 = *(const bf16x8*)(ar0 + ks * 32);
        bf16x8 a1 = *(const bf16x8*)(ar1 + ks * 32);
#pragma unroll
        for (int ns = 0; ns < 3; ns++) {
            bf16x8 bfr = *(const bf16x8*)(w2p + ((size_t)(ns * 8 + ks) * 64 + lane) * 8);
            acc[0][ns] = __builtin_amdgcn_mfma_f32_16x16x32_bf16(a0, bfr, acc[0][ns], 0, 0, 0);
            acc[1][ns] = __builtin_amdgcn_mfma_f32_16x16x32_bf16(a1, bfr, acc[1][ns], 0, 0, 0);
        }
    }
#pragma unroll
    for (int t = 0; t < 2; t++) {
#pragma unroll
        for (int ns = 0; ns < 3; ns++) {
            int col = ns * 16 + lrow;
            if (col < LABELS) {
                float bv = b2[col];
#pragma unroll
                for (int i = 0; i < 4; i++) {
                    int r = row0 + t * 16 + lgrp * 4 + i;
                    if (r < N_NODES)                       // d_out: exact size
                        out[(size_t)r * LABELS + col] = acc[t][ns][i] + bv;
                }
            }
        }
    }
}

// ---------------------------------------------------------------------------
extern "C" void kernel_launch(void* const* d_in, const int* in_sizes, int n_in,
                              void* d_out, int out_size, void* d_ws, size_t ws_size,
                              hipStream_t stream) {
    const float* x      = (const float*)d_in[0];
    const int*   ei     = (const int*)d_in[1];
    const float* selfk  = (const float*)d_in[2];
    const float* nbrk   = (const float*)d_in[3];
    const float* biases = (const float*)d_in[4];
    const float* w1     = (const float*)d_in[5];
    const float* b1     = (const float*)d_in[6];
    const float* w2     = (const float*)d_in[7];
    const float* b2     = (const float*)d_in[8];
    float* out = (float*)d_out;

    const int* row = ei;             // targets
    const int* col = ei + N_EDGES;   // sources

    char* ws = (char*)d_ws;
    size_t off = 0;
    auto alloc = [&](size_t bytes) -> char* {
        char* p = ws + off;
        off = (off + bytes + 255) & ~(size_t)255;
        return p;
    };
    int*   deg       = (int*)  alloc((size_t)N_NODES * 4);
    int*   rowstart  = (int*)  alloc((size_t)N_NODES * 4);
    float* inv_deg   = (float*)alloc((size_t)N_NODES * 4);
    int*   bucket_cursor = (int*)alloc(256 * 4);
    int*   bucket_base   = (int*)alloc(256 * 4);
    int*   csr_col   = (int*)  alloc((size_t)N_EDGES * 4);
    __hip_bfloat16* wpack  = (__hip_bfloat16*)alloc(PK_TOTAL * 2);
    __hip_bfloat16* xb     = (__hip_bfloat16*)alloc((size_t)N_PAD * D_FEAT * 2);
    __hip_bfloat16* hA     = (__hip_bfloat16*)alloc((size_t)N_PAD * D_FEAT * 2);
    __hip_bfloat16* hB     = (__hip_bfloat16*)alloc((size_t)N_PAD * D_FEAT * 2);
    __hip_bfloat16* nbrbuf = (__hip_bfloat16*)alloc((size_t)N_PAD * D_FEAT * 2);
    __hip_bfloat16* hidden = (__hip_bfloat16*)alloc((size_t)N_PAD * HIDDEN * 2);
    // staging (4.4 MB) aliases hidden (25.7 MB): dead before mlp1 writes hidden.
    uint32_t* staged = (uint32_t*)hidden;

    hipMemsetAsync(bucket_cursor, 0, 256 * 4, stream);

    const int scat_blocks = (N_EDGES + EDGES_PER_BLK - 1) / EDGES_PER_BLK;  // 196
    bucket_scatter_kernel<<<scat_blocks, 1024, 0, stream>>>(row, col, bucket_cursor, staged);
    bucket_scan_kernel<<<1, 256, 0, stream>>>(bucket_cursor, bucket_base);
    bucket_fill_kernel<<<NBUCK, 1024, 0, stream>>>(staged, bucket_cursor, bucket_base,
                                                   deg, rowstart, inv_deg, csr_col);

    xcast_kernel<<<(N_NODES * D_FEAT / 4 + 255) / 256, 256, 0, stream>>>(x, xb);
    dim3 pgrid(16, 8);
    pack_all_kernel<<<pgrid, 256, 0, stream>>>(selfk, nbrk, w1, w2, wpack);

    const int agg_blocks   = N_NODES / 8;                  // 2 nodes/wave, 4 waves/block
    const int layer_blocks = (N_NODES + 63) / 64;          // 64 rows/block
    const int mlp_blocks   = N_PAD / 128;                  // 128 rows/block

    const __hip_bfloat16* hcur = xb;
    __hip_bfloat16* bufs[3] = {hA, hB, hA};
    for (int L = 0; L < 3; L++) {
        agg2_kernel<<<agg_blocks, 256, 0, stream>>>(hcur, csr_col, rowstart, deg,
                                                    inv_deg, nbrbuf);
        layer_mfma_kernel<<<layer_blocks, 256, 0, stream>>>(
            hcur, nbrbuf, wpack + PK_SELF(L), wpack + PK_NBR(L),
            biases + (size_t)L * (2 * HALF), bufs[L]);
        hcur = bufs[L];
    }

    mlp1_mfma_kernel<<<mlp_blocks, 256, 0, stream>>>(hcur, wpack + PK_W1, b1, hidden);
    mlp2_mfma_kernel<<<mlp_blocks, 256, 0, stream>>>(hidden, wpack + PK_W2, b2, out);
}

// Round 9
// 260.123 us; speedup vs baseline: 3.3803x; 1.0762x over previous
//
#include <hip/hip_runtime.h>
#include <hip/hip_bf16.h>
#include <cstdint>
#include <cstddef>

#define N_NODES 50000
#define N_PAD   50176    // padded rows for guard-free GEMM tiles
#define N_EDGES 800000
#define D_FEAT  128
#define HALF    64
#define HIDDEN  256
#define LABELS  40

#define NBUCK 196        // ceil(50000/256) buckets of 256 nodes (node>>8)
#define BCAP  5632       // staging cap per bucket; E[cnt]=4096, sigma~64 (24 sigma)
#define EDGES_PER_BLK 4096

typedef __attribute__((ext_vector_type(8))) short bf16x8;
typedef __attribute__((ext_vector_type(4))) float f32x4;

// Packed-weight layout offsets (in bf16 elements).
#define PK_SELF(L) ((size_t)(L) * 8192)
#define PK_NBR(L)  (24576 + (size_t)(L) * 8192)
#define PK_W1      49152
#define PK_W2      81920
#define PK_TOTAL   94208

__device__ inline uint16_t f2bf_bits(float f) {
    __hip_bfloat16 b = __float2bfloat16(f);
    uint16_t u; __builtin_memcpy(&u, &b, 2); return u;
}

// ---------------------------------------------------------------------------
// CSR build phase 1: bucket scatter. 196 blocks x 4096 edges.
// ---------------------------------------------------------------------------
__global__ __launch_bounds__(1024) void bucket_scatter_kernel(
        const int* __restrict__ row, const int* __restrict__ col,
        int* __restrict__ bucket_cursor, uint32_t* __restrict__ staged) {
    __shared__ int hist[NBUCK];
    __shared__ int hbase[NBUCK];
    int tid  = threadIdx.x;
    int e0   = blockIdx.x * EDGES_PER_BLK;
    int eend = e0 + EDGES_PER_BLK; if (eend > N_EDGES) eend = N_EDGES;

    for (int i = tid; i < NBUCK; i += 1024) hist[i] = 0;
    __syncthreads();

    int rr[4], cc[4]; int ne = 0;
    for (int e = e0 + tid; e < eend; e += 1024) {
        rr[ne] = row[e]; cc[ne] = col[e]; ne++;
    }
    for (int i = 0; i < ne; i++) atomicAdd(&hist[rr[i] >> 8], 1);
    __syncthreads();

    for (int i = tid; i < NBUCK; i += 1024) {
        hbase[i] = atomicAdd(&bucket_cursor[i], hist[i]);
        hist[i]  = 0;
    }
    __syncthreads();

    for (int i = 0; i < ne; i++) {
        int b   = rr[i] >> 8;
        int off = atomicAdd(&hist[b], 1);
        int pos = hbase[b] + off;
        if (pos < BCAP)
            staged[(size_t)b * BCAP + pos] =
                ((uint32_t)(rr[i] & 255) << 16) | (uint32_t)cc[i];
    }
}

// ---------------------------------------------------------------------------
// CSR build phase 1.5: exclusive scan of the 196 bucket sizes. One block.
// ---------------------------------------------------------------------------
__global__ void bucket_scan_kernel(const int* __restrict__ bucket_cursor,
                                   int* __restrict__ bucket_base) {
    __shared__ int wt[4];
    int tid = threadIdx.x, lane = tid & 63, wid = tid >> 6;
    int v = (tid < NBUCK) ? bucket_cursor[tid] : 0;
    int s = v;
#pragma unroll
    for (int off = 1; off < 64; off <<= 1) {
        int t = __shfl_up(s, off, 64);
        if (lane >= off) s += t;
    }
    if (lane == 63) wt[wid] = s;
    __syncthreads();
    if (tid == 0) { int a = 0; for (int i = 0; i < 4; i++) { int t = wt[i]; wt[i] = a; a += t; } }
    __syncthreads();
    if (tid < NBUCK) bucket_base[tid] = s - v + wt[wid];
}

// ---------------------------------------------------------------------------
// CSR build phase 2: one block per bucket -> deg/rowstart/inv_deg/csr_col.
// ---------------------------------------------------------------------------
__global__ __launch_bounds__(1024) void bucket_fill_kernel(
        const uint32_t* __restrict__ staged, const int* __restrict__ bucket_cursor,
        const int* __restrict__ bucket_base, int* __restrict__ deg,
        int* __restrict__ rowstart, float* __restrict__ inv_deg,
        int* __restrict__ csr_col) {
    __shared__ int cnt[256];
    __shared__ int excl[256];
    __shared__ int wt[4];
    __shared__ int seg[BCAP];
    int b   = blockIdx.x;
    int tid = threadIdx.x;
    int total = bucket_cursor[b]; if (total > BCAP) total = BCAP;
    int gbase = bucket_base[b];
    const uint32_t* st = staged + (size_t)b * BCAP;

    if (tid < 256) cnt[tid] = 0;
    __syncthreads();
    for (int i = tid; i < total; i += 1024) atomicAdd(&cnt[st[i] >> 16], 1);
    __syncthreads();

    int lane = tid & 63, wid = tid >> 6;
    int v = 0, s = 0;
    if (tid < 256) {
        v = cnt[tid]; s = v;
#pragma unroll
        for (int off = 1; off < 64; off <<= 1) {
            int t = __shfl_up(s, off, 64);
            if (lane >= off) s += t;
        }
        if (lane == 63) wt[wid] = s;
    }
    __syncthreads();
    if (tid == 0) { int a = 0; for (int i = 0; i < 4; i++) { int t = wt[i]; wt[i] = a; a += t; } }
    __syncthreads();
    if (tid < 256) {
        int ex = s - v + wt[wid];
        excl[tid] = ex;
        int node = (b << 8) + tid;
        if (node < N_NODES) {
            deg[node]      = v;
            rowstart[node] = gbase + ex;
            inv_deg[node]  = 1.0f / fmaxf((float)v, 1.0f);
        }
    }
    __syncthreads();
    for (int i = tid; i < total; i += 1024) {
        uint32_t u = st[i];
        int p = atomicAdd(&excl[u >> 16], 1);
        seg[p] = (int)(u & 0xffffu);
    }
    __syncthreads();
    for (int i = tid; i < total; i += 1024) csr_col[gbase + i] = seg[i];
}

// ---------------------------------------------------------------------------
// x (fp32) -> bf16
// ---------------------------------------------------------------------------
__global__ __launch_bounds__(256) void xcast_kernel(
        const float* __restrict__ x, __hip_bfloat16* __restrict__ xb) {
    size_t i = (size_t)(blockIdx.x * blockDim.x + threadIdx.x) * 4;
    if (i >= (size_t)N_NODES * D_FEAT) return;
    float4 v = *(const float4*)(x + i);
    uint2 p;
    p.x = (uint32_t)f2bf_bits(v.x) | ((uint32_t)f2bf_bits(v.y) << 16);
    p.y = (uint32_t)f2bf_bits(v.z) | ((uint32_t)f2bf_bits(v.w) << 16);
    *(uint2*)((uint16_t*)xb + i) = p;
}

// ---------------------------------------------------------------------------
// Pack all weights to bf16 in MFMA B-fragment order.
//   pack[((ns*ksteps + ks)*64 + l)*8 + j] = W[ks*32 + (l>>4)*8 + j][ns*16 + (l&15)]
// ---------------------------------------------------------------------------
__global__ __launch_bounds__(256) void pack_all_kernel(
        const float* __restrict__ selfk, const float* __restrict__ nbrk,
        const float* __restrict__ w1, const float* __restrict__ w2,
        __hip_bfloat16* __restrict__ wpack) {
    int m = blockIdx.y;
    const float* W; int K, Ncols, Npad; size_t dstoff;
    if (m < 3)      { W = selfk + (size_t)m*D_FEAT*HALF;      K=128; Ncols=64;  Npad=64;  dstoff = PK_SELF(m); }
    else if (m < 6) { W = nbrk  + (size_t)(m-3)*D_FEAT*HALF;  K=128; Ncols=64;  Npad=64;  dstoff = PK_NBR(m-3); }
    else if (m == 6){ W = w1;                                 K=128; Ncols=256; Npad=256; dstoff = PK_W1; }
    else            { W = w2;                                 K=256; Ncols=40;  Npad=48;  dstoff = PK_W2; }
    int ksteps = K / 32;
    int total  = ksteps * (Npad / 16) * 64;
    int t = blockIdx.x * blockDim.x + threadIdx.x;
    if (t >= total) return;
    int lane = t & 63;
    int rest = t >> 6;
    int ks   = rest % ksteps;
    int ns   = rest / ksteps;
    int colb = ns * 16 + (lane & 15);
    int kb   = ks * 32 + (lane >> 4) * 8;
    __hip_bfloat16* dst = wpack + dstoff + (size_t)t * 8;
#pragma unroll
    for (int j = 0; j < 8; j++) {
        float v = (colb < Ncols) ? W[(size_t)(kb + j) * Ncols + colb] : 0.f;
        dst[j] = __float2bfloat16(v);
    }
}

// ---------------------------------------------------------------------------
// Mean-neighbor aggregation: FOUR nodes per wave, 16 lanes/node, dwordx4
// (16B) loads -> one VMEM inst covers 4 edge-rows. csr_col indices are
// software-pipelined (next pair prefetched while current rows load) to break
// the index->gather latency chain. Per-element accumulation order identical
// to r8's agg2 (bit-identical output).
// ---------------------------------------------------------------------------
__global__ __launch_bounds__(256) void agg4_kernel(
        const __hip_bfloat16* __restrict__ h, const int* __restrict__ csr_col,
        const int* __restrict__ rowstart, const int* __restrict__ deg,
        const float* __restrict__ inv_deg, __hip_bfloat16* __restrict__ nbr) {
    int gid  = blockIdx.x * blockDim.x + threadIdx.x;
    int wnum = gid >> 6;
    int lane = threadIdx.x & 63;
    int sub  = lane >> 4;                // node slot within wave (0..3)
    int sl   = lane & 15;                // covers dwords [4*sl, 4*sl+3] of the row
    int node = wnum * 4 + sub;           // grid exact: 12500 waves * 4 = 50000
    int start = rowstart[node];
    int d     = deg[node];
    const uint32_t* hw = (const uint32_t*)h;   // row = 64 dwords
    float acc[8] = {};
    if (d > 0) {
        int last = start + d - 1;
        int s0 = csr_col[start];
        int s1 = csr_col[min(start + 1, last)];
        int j = 0;
        for (; j + 2 <= d; j += 2) {
            int p0 = csr_col[min(start + j + 2, last)];
            int p1 = csr_col[min(start + j + 3, last)];
            uint4 u = *(const uint4*)(hw + (size_t)s0 * 64 + sl * 4);
            uint4 v = *(const uint4*)(hw + (size_t)s1 * 64 + sl * 4);
            acc[0] += __uint_as_float(u.x << 16);
            acc[1] += __uint_as_float(u.x & 0xffff0000u);
            acc[2] += __uint_as_float(u.y << 16);
            acc[3] += __uint_as_float(u.y & 0xffff0000u);
            acc[4] += __uint_as_float(u.z << 16);
            acc[5] += __uint_as_float(u.z & 0xffff0000u);
            acc[6] += __uint_as_float(u.w << 16);
            acc[7] += __uint_as_float(u.w & 0xffff0000u);
            acc[0] += __uint_as_float(v.x << 16);
            acc[1] += __uint_as_float(v.x & 0xffff0000u);
            acc[2] += __uint_as_float(v.y << 16);
            acc[3] += __uint_as_float(v.y & 0xffff0000u);
            acc[4] += __uint_as_float(v.z << 16);
            acc[5] += __uint_as_float(v.z & 0xffff0000u);
            acc[6] += __uint_as_float(v.w << 16);
            acc[7] += __uint_as_float(v.w & 0xffff0000u);
            s0 = p0; s1 = p1;
        }
        if (j < d) {
            uint4 u = *(const uint4*)(hw + (size_t)s0 * 64 + sl * 4);
            acc[0] += __uint_as_float(u.x << 16);
            acc[1] += __uint_as_float(u.x & 0xffff0000u);
            acc[2] += __uint_as_float(u.y << 16);
            acc[3] += __uint_as_float(u.y & 0xffff0000u);
            acc[4] += __uint_as_float(u.z << 16);
            acc[5] += __uint_as_float(u.z & 0xffff0000u);
            acc[6] += __uint_as_float(u.w << 16);
            acc[7] += __uint_as_float(u.w & 0xffff0000u);
        }
    }
    float inv = inv_deg[node];
    uint4 p;
    p.x = (uint32_t)f2bf_bits(acc[0] * inv) | ((uint32_t)f2bf_bits(acc[1] * inv) << 16);
    p.y = (uint32_t)f2bf_bits(acc[2] * inv) | ((uint32_t)f2bf_bits(acc[3] * inv) << 16);
    p.z = (uint32_t)f2bf_bits(acc[4] * inv) | ((uint32_t)f2bf_bits(acc[5] * inv) << 16);
    p.w = (uint32_t)f2bf_bits(acc[6] * inv) | ((uint32_t)f2bf_bits(acc[7] * inv) << 16);
    *(uint4*)((uint32_t*)nbr + (size_t)node * 64 + sl * 4) = p;
}

// ---------------------------------------------------------------------------
// Layer GEMM (MFMA), fused halves: out[N,128] = relu([h@Wself | nbr@Wnbr]+b).
// One wave does 32 rows x both halves: 4 A-frags (2 from h, 2 from nbr) feed
// 8 B-subtiles. 392 blocks (vs 784): single cohort at 2 blocks/CU. Same math
// and same inputs/outputs as r8's layer_mfma_kernel.
// ---------------------------------------------------------------------------
__global__ __launch_bounds__(256, 2) void layer_fused_kernel(
        const __hip_bfloat16* __restrict__ h, const __hip_bfloat16* __restrict__ nbr,
        const __hip_bfloat16* __restrict__ wpack_self,
        const __hip_bfloat16* __restrict__ wpack_nbr,
        const float* __restrict__ bias, __hip_bfloat16* __restrict__ out) {
    int wave = threadIdx.x >> 6, lane = threadIdx.x & 63;
    int row0 = blockIdx.x * 128 + wave * 32;
    int lrow = lane & 15, lgrp = lane >> 4;
    const __hip_bfloat16* hr0 = h   + (size_t)(row0 + lrow) * D_FEAT + lgrp * 8;
    const __hip_bfloat16* hr1 = hr0 + (size_t)16 * D_FEAT;
    const __hip_bfloat16* nr0 = nbr + (size_t)(row0 + lrow) * D_FEAT + lgrp * 8;
    const __hip_bfloat16* nr1 = nr0 + (size_t)16 * D_FEAT;

    f32x4 accS[2][4] = {};
    f32x4 accN[2][4] = {};
#pragma unroll
    for (int ks = 0; ks < 4; ks++) {
        bf16x8 ah0 = *(const bf16x8*)(hr0 + ks * 32);
        bf16x8 ah1 = *(const bf16x8*)(hr1 + ks * 32);
        bf16x8 an0 = *(const bf16x8*)(nr0 + ks * 32);
        bf16x8 an1 = *(const bf16x8*)(nr1 + ks * 32);
#pragma unroll
        for (int ns = 0; ns < 4; ns++) {
            bf16x8 bs = *(const bf16x8*)(wpack_self + ((size_t)(ns * 4 + ks) * 64 + lane) * 8);
            accS[0][ns] = __builtin_amdgcn_mfma_f32_16x16x32_bf16(ah0, bs, accS[0][ns], 0, 0, 0);
            accS[1][ns] = __builtin_amdgcn_mfma_f32_16x16x32_bf16(ah1, bs, accS[1][ns], 0, 0, 0);
            bf16x8 bn = *(const bf16x8*)(wpack_nbr + ((size_t)(ns * 4 + ks) * 64 + lane) * 8);
            accN[0][ns] = __builtin_amdgcn_mfma_f32_16x16x32_bf16(an0, bn, accN[0][ns], 0, 0, 0);
            accN[1][ns] = __builtin_amdgcn_mfma_f32_16x16x32_bf16(an1, bn, accN[1][ns], 0, 0, 0);
        }
    }
#pragma unroll
    for (int t = 0; t < 2; t++) {
#pragma unroll
        for (int ns = 0; ns < 4; ns++) {
            int colS = ns * 16 + lrow;
            int colN = HALF + colS;
            float bvS = bias[colS];
            float bvN = bias[colN];
#pragma unroll
            for (int i = 0; i < 4; i++) {
                int r = row0 + t * 16 + lgrp * 4 + i;     // < N_PAD, unguarded
                out[(size_t)r * D_FEAT + colS] =
                    __float2bfloat16(fmaxf(accS[t][ns][i] + bvS, 0.f));
                out[(size_t)r * D_FEAT + colN] =
                    __float2bfloat16(fmaxf(accN[t][ns][i] + bvN, 0.f));
            }
        }
    }
}

// ---------------------------------------------------------------------------
// MLP1 (MFMA): hidden[N,256] = relu(h @ W1 + b1), bf16 out. 32 rows/wave.
// ---------------------------------------------------------------------------
__global__ __launch_bounds__(256, 2) void mlp1_mfma_kernel(
        const __hip_bfloat16* __restrict__ h, const __hip_bfloat16* __restrict__ w1p,
        const float* __restrict__ b1, __hip_bfloat16* __restrict__ hidden) {
    int wave = threadIdx.x >> 6, lane = threadIdx.x & 63;
    int row0 = blockIdx.x * 128 + wave * 32;
    int lrow = lane & 15, lgrp = lane >> 4;
    const __hip_bfloat16* ar0 = h + (size_t)(row0 + lrow) * D_FEAT + lgrp * 8;
    const __hip_bfloat16* ar1 = ar0 + (size_t)16 * D_FEAT;

    f32x4 acc[2][16] = {};
#pragma unroll 1
    for (int ks = 0; ks < 4; ks++) {
        bf16x8 a0 = *(const bf16x8*)(ar0 + ks * 32);
        bf16x8 a1 = *(const bf16x8*)(ar1 + ks * 32);
#pragma unroll
        for (int ns = 0; ns < 16; ns++) {
            bf16x8 bfr = *(const bf16x8*)(w1p + ((size_t)(ns * 4 + ks) * 64 + lane) * 8);
            acc[0][ns] = __builtin_amdgcn_mfma_f32_16x16x32_bf16(a0, bfr, acc[0][ns], 0, 0, 0);
            acc[1][ns] = __builtin_amdgcn_mfma_f32_16x16x32_bf16(a1, bfr, acc[1][ns], 0, 0, 0);
        }
    }
#pragma unroll
    for (int t = 0; t < 2; t++) {
#pragma unroll
        for (int ns = 0; ns < 16; ns++) {
            int col = ns * 16 + lrow;
            float bv = b1[col];
#pragma unroll
            for (int i = 0; i < 4; i++) {
                int r = row0 + t * 16 + lgrp * 4 + i;     // < N_PAD, unguarded
                hidden[(size_t)r * HIDDEN + col] =
                    __float2bfloat16(fmaxf(acc[t][ns][i] + bv, 0.f));
            }
        }
    }
}

// ---------------------------------------------------------------------------
// MLP2 (MFMA): out[N,40] = hidden @ W2 + b2 (fp32 out). 32 rows/wave.
// ---------------------------------------------------------------------------
__global__ __launch_bounds__(256, 2) void mlp2_mfma_kernel(
        const __hip_bfloat16* __restrict__ hidden, const __hip_bfloat16* __restrict__ w2p,
        const float* __restrict__ b2, float* __restrict__ out) {
    int wave = threadIdx.x >> 6, lane = threadIdx.x & 63;
    int row0 = blockIdx.x * 128 + wave * 32;
    int lrow = lane & 15, lgrp = lane >> 4;
    const __hip_bfloat16* ar0 = hidden + (size_t)(row0 + lrow) * HIDDEN + lgrp * 8;
    const __hip_bfloat16* ar1 = ar0 + (size_t)16 * HIDDEN;

    f32x4 acc[2][3] = {};
#pragma unroll
    for (int ks = 0; ks < 8; ks++) {
        bf16x8 a0 = *(const bf16x8*)(ar0 + ks * 32);
        bf16x8 a1 = *(const bf16x8*)(ar1 + ks * 32);
#pragma unroll
        for (int ns = 0; ns < 3; ns++) {
            bf16x8 bfr = *(const bf16x8*)(w2p + ((size_t)(ns * 8 + ks) * 64 + lane) * 8);
            acc[0][ns] = __builtin_amdgcn_mfma_f32_16x16x32_bf16(a0, bfr, acc[0][ns], 0, 0, 0);
            acc[1][ns] = __builtin_amdgcn_mfma_f32_16x16x32_bf16(a1, bfr, acc[1][ns], 0, 0, 0);
        }
    }
#pragma unroll
    for (int t = 0; t < 2; t++) {
#pragma unroll
        for (int ns = 0; ns < 3; ns++) {
            int col = ns * 16 + lrow;
            if (col < LABELS) {
                float bv = b2[col];
#pragma unroll
                for (int i = 0; i < 4; i++) {
                    int r = row0 + t * 16 + lgrp * 4 + i;
                    if (r < N_NODES)                       // d_out: exact size
                        out[(size_t)r * LABELS + col] = acc[t][ns][i] + bv;
                }
            }
        }
    }
}

// ---------------------------------------------------------------------------
extern "C" void kernel_launch(void* const* d_in, const int* in_sizes, int n_in,
                              void* d_out, int out_size, void* d_ws, size_t ws_size,
                              hipStream_t stream) {
    const float* x      = (const float*)d_in[0];
    const int*   ei     = (const int*)d_in[1];
    const float* selfk  = (const float*)d_in[2];
    const float* nbrk   = (const float*)d_in[3];
    const float* biases = (const float*)d_in[4];
    const float* w1     = (const float*)d_in[5];
    const float* b1     = (const float*)d_in[6];
    const float* w2     = (const float*)d_in[7];
    const float* b2     = (const float*)d_in[8];
    float* out = (float*)d_out;

    const int* row = ei;             // targets
    const int* col = ei + N_EDGES;   // sources

    char* ws = (char*)d_ws;
    size_t off = 0;
    auto alloc = [&](size_t bytes) -> char* {
        char* p = ws + off;
        off = (off + bytes + 255) & ~(size_t)255;
        return p;
    };
    int*   deg       = (int*)  alloc((size_t)N_NODES * 4);
    int*   rowstart  = (int*)  alloc((size_t)N_NODES * 4);
    float* inv_deg   = (float*)alloc((size_t)N_NODES * 4);
    int*   bucket_cursor = (int*)alloc(256 * 4);
    int*   bucket_base   = (int*)alloc(256 * 4);
    int*   csr_col   = (int*)  alloc((size_t)N_EDGES * 4);
    __hip_bfloat16* wpack  = (__hip_bfloat16*)alloc(PK_TOTAL * 2);
    __hip_bfloat16* xb     = (__hip_bfloat16*)alloc((size_t)N_PAD * D_FEAT * 2);
    __hip_bfloat16* hA     = (__hip_bfloat16*)alloc((size_t)N_PAD * D_FEAT * 2);
    __hip_bfloat16* hB     = (__hip_bfloat16*)alloc((size_t)N_PAD * D_FEAT * 2);
    __hip_bfloat16* nbrbuf = (__hip_bfloat16*)alloc((size_t)N_PAD * D_FEAT * 2);
    __hip_bfloat16* hidden = (__hip_bfloat16*)alloc((size_t)N_PAD * HIDDEN * 2);
    // staging (4.4 MB) aliases hidden (25.7 MB): dead before mlp1 writes hidden.
    uint32_t* staged = (uint32_t*)hidden;

    hipMemsetAsync(bucket_cursor, 0, 256 * 4, stream);

    const int scat_blocks = (N_EDGES + EDGES_PER_BLK - 1) / EDGES_PER_BLK;  // 196
    bucket_scatter_kernel<<<scat_blocks, 1024, 0, stream>>>(row, col, bucket_cursor, staged);
    bucket_scan_kernel<<<1, 256, 0, stream>>>(bucket_cursor, bucket_base);
    bucket_fill_kernel<<<NBUCK, 1024, 0, stream>>>(staged, bucket_cursor, bucket_base,
                                                   deg, rowstart, inv_deg, csr_col);

    xcast_kernel<<<(N_NODES * D_FEAT / 4 + 255) / 256, 256, 0, stream>>>(x, xb);
    dim3 pgrid(16, 8);
    pack_all_kernel<<<pgrid, 256, 0, stream>>>(selfk, nbrk, w1, w2, wpack);

    const int agg_blocks   = N_NODES / 16;                 // 4 nodes/wave, 4 waves/block
    const int layer_blocks = N_PAD / 128;                  // 128 rows/block, fused halves
    const int mlp_blocks   = N_PAD / 128;

    const __hip_bfloat16* hcur = xb;
    __hip_bfloat16* bufs[3] = {hA, hB, hA};
    for (int L = 0; L < 3; L++) {
        agg4_kernel<<<agg_blocks, 256, 0, stream>>>(hcur, csr_col, rowstart, deg,
                                                    inv_deg, nbrbuf);
        layer_fused_kernel<<<layer_blocks, 256, 0, stream>>>(
            hcur, nbrbuf, wpack + PK_SELF(L), wpack + PK_NBR(L),
            biases + (size_t)L * (2 * HALF), bufs[L]);
        hcur = bufs[L];
    }

    mlp1_mfma_kernel<<<mlp_blocks, 256, 0, stream>>>(hcur, wpack + PK_W1, b1, hidden);
    mlp2_mfma_kernel<<<mlp_blocks, 256, 0, stream>>>(hidden, wpack + PK_W2, b2, out);
}